// Round 16
// baseline (267.810 us; speedup 1.0000x reference)
//
#include <hip/hip_runtime.h>

#define NN 30000
#define EE 300000
#define HH 4
#define SLOPE 0.2f
#define SCAN_NB 15        // ceil(30000 / 2048)

typedef _Float16 f16;
typedef f16 f16x8 __attribute__((ext_vector_type(8)));
typedef float f32x4 __attribute__((ext_vector_type(4)));

// ---------------- prep: z<3 -> W layer-z f16 transpose; z==3 -> zero deg ----------------
__global__ __launch_bounds__(256) void prep_k(const float* __restrict__ W0,
                                              const float* __restrict__ W1,
                                              const float* __restrict__ W2,
                                              f16* __restrict__ Wh,
                                              int4* __restrict__ deg4) {
    const int z = blockIdx.z;
    if (z == 3) {
        const int base = (blockIdx.y * 8 + blockIdx.x) * 256 + threadIdx.x;  // 4096 threads
        for (int j = base; j < 2 * NN / 4; j += 4096) deg4[j] = make_int4(0, 0, 0, 0);
        return;
    }
    const int t = blockIdx.y;
    const float* W = (z == 0) ? W0 : ((z == 1) ? W1 : W2);
    f16* Whl = Wh + (size_t)z * 2 * 16384;
    const int i0 = blockIdx.x * 2048;
    #pragma unroll
    for (int j = 0; j < 8; ++j) {
        const int i = i0 + threadIdx.x + j * 256;     // i = k*128 + col (coalesced read)
        const int k = i >> 7, col = i & 127;
        Whl[t * 16384 + col * 128 + k] = (f16)W[t * 16384 + i];
    }
}

// ---------------- MFMA GEMM: feat16[t][n][:] = A @ W[t], fused el/er epilogue ----------------
// 1D grid 938: bx = blockIdx.x>>1, et = blockIdx.x&1 (adjacent etype blocks share A via L2).
#define APAD 136
__global__ __launch_bounds__(256) void gemm_mfma(const f16* __restrict__ Ah,
                                                 const float* __restrict__ Af,
                                                 const int use_f32,
                                                 const f16* __restrict__ Whbase,
                                                 const float* __restrict__ albase,
                                                 const float* __restrict__ arbase,
                                                 f16* __restrict__ featbase,
                                                 float* __restrict__ elbase,
                                                 float* __restrict__ erbase) {
    __shared__ f16 Bsl[128 * APAD];
    const int bx = blockIdx.x >> 1;
    const int et = blockIdx.x & 1;
    const f16* Wh = Whbase + et * 16384;
    f16* feat = featbase + (size_t)et * NN * 128;
    const int row0 = bx * 64;
    const int t = threadIdx.x;

    #pragma unroll
    for (int j = 0; j < 8; ++j) {
        const int idx = t + j * 256;            // idx = col*16 + k16
        const int col = idx >> 4, k16 = idx & 15;
        *reinterpret_cast<float4*>(&Bsl[col * APAD + k16 * 8]) =
            *reinterpret_cast<const float4*>(Wh + col * 128 + k16 * 8);
    }
    __syncthreads();

    const int w = t >> 6, lane = t & 63;
    const int r = lane & 15, g = lane >> 4;
    const int mb = w * 16;
    const int rowa = min(row0 + mb + r, NN - 1);
    f32x4 acc[8];
    #pragma unroll
    for (int nt = 0; nt < 8; ++nt) acc[nt] = (f32x4){0.f, 0.f, 0.f, 0.f};

    #pragma unroll
    for (int ks = 0; ks < 4; ++ks) {
        f16x8 av;
        if (use_f32) {
            const float4 a0 =
                *reinterpret_cast<const float4*>(Af + (size_t)rowa * 128 + ks * 32 + g * 8);
            const float4 a1 =
                *reinterpret_cast<const float4*>(Af + (size_t)rowa * 128 + ks * 32 + g * 8 + 4);
            av[0] = (f16)a0.x; av[1] = (f16)a0.y; av[2] = (f16)a0.z; av[3] = (f16)a0.w;
            av[4] = (f16)a1.x; av[5] = (f16)a1.y; av[6] = (f16)a1.z; av[7] = (f16)a1.w;
        } else {
            av = *reinterpret_cast<const f16x8*>(Ah + (size_t)rowa * 128 + ks * 32 + g * 8);
        }
        #pragma unroll
        for (int nt = 0; nt < 8; ++nt) {
            const f16x8 bv =
                *reinterpret_cast<const f16x8*>(&Bsl[(nt * 16 + r) * APAD + ks * 32 + g * 8]);
            acc[nt] = __builtin_amdgcn_mfma_f32_16x16x32_f16(av, bv, acc[nt], 0, 0, 0);
        }
    }

    float alv[8], arv[8];
    #pragma unroll
    for (int nt = 0; nt < 8; ++nt) {            // col = nt*16 + r
        alv[nt] = albase[et * 128 + nt * 16 + r];
        arv[nt] = arbase[et * 128 + nt * 16 + r];
    }
    #pragma unroll
    for (int p = 0; p < 4; ++p) {
        const int row = row0 + mb + g * 4 + p;
        const bool ok = row < NN;
        if (ok) {
            #pragma unroll
            for (int nt = 0; nt < 8; ++nt)
                feat[(size_t)row * 128 + nt * 16 + r] = (f16)acc[nt][p];
        }
        #pragma unroll
        for (int h = 0; h < 4; ++h) {
            float pl = fmaf(acc[2 * h][p], alv[2 * h], acc[2 * h + 1][p] * alv[2 * h + 1]);
            float pr = fmaf(acc[2 * h][p], arv[2 * h], acc[2 * h + 1][p] * arv[2 * h + 1]);
            pl += __shfl_xor(pl, 1); pl += __shfl_xor(pl, 2);
            pl += __shfl_xor(pl, 4); pl += __shfl_xor(pl, 8);
            pr += __shfl_xor(pr, 1); pr += __shfl_xor(pr, 2);
            pr += __shfl_xor(pr, 4); pr += __shfl_xor(pr, 8);
            if (ok && r == 0) {
                elbase[et * NN * HH + row * HH + h] = pl;
                erbase[et * NN * HH + row * HH + h] = pr;
            }
        }
    }
}

// ---------------- CSR build: histogram, int4-vectorized ----------------
__global__ __launch_bounds__(256) void hist4_k(const int* __restrict__ dst0,
                                               const int* __restrict__ dst1,
                                               int* __restrict__ deg) {
    const int i = blockIdx.x * 256 + threadIdx.x;   // i < EE/4
    if (i >= EE / 4) return;
    const int t = blockIdx.y;
    const int4 d = reinterpret_cast<const int4*>(t ? dst1 : dst0)[i];
    int* dg = deg + t * NN;
    atomicAdd(&dg[d.x], 1);
    atomicAdd(&dg[d.y], 1);
    atomicAdd(&dg[d.z], 1);
    atomicAdd(&dg[d.w], 1);
}

// ---------------- multi-block exclusive scan, phase 1 ----------------
__global__ __launch_bounds__(256) void scan1_k(const int* __restrict__ deg,
                                               int* __restrict__ offs,
                                               int* __restrict__ blocksum) {
    const int t = blockIdx.y, b = blockIdx.x;
    const int* d = deg + t * NN;
    int* o = offs + t * (NN + 1);
    const int base = b * 2048 + threadIdx.x * 8;
    int v[8];
    int s = 0;
    #pragma unroll
    for (int j = 0; j < 8; ++j) {
        const int i = base + j;
        v[j] = (i < NN) ? d[i] : 0;
        s += v[j];
    }
    __shared__ int buf[256];
    buf[threadIdx.x] = s;
    __syncthreads();
    #pragma unroll
    for (int ofs = 1; ofs < 256; ofs <<= 1) {
        const int add = (threadIdx.x >= (unsigned)ofs) ? buf[threadIdx.x - ofs] : 0;
        __syncthreads();
        buf[threadIdx.x] += add;
        __syncthreads();
    }
    int run = buf[threadIdx.x] - s;
    #pragma unroll
    for (int j = 0; j < 8; ++j) {
        const int i = base + j;
        if (i < NN) o[i] = run;
        run += v[j];
    }
    if (threadIdx.x == 255) blocksum[t * SCAN_NB + b] = buf[255];
}

// ---------------- scan phase 2+3 merged ----------------
__global__ __launch_bounds__(256) void scan3b_k(int* __restrict__ offs,
                                                const int* __restrict__ blocksum,
                                                int* __restrict__ cursor) {
    const int t = blockIdx.y, b = blockIdx.x;
    int boff = 0;
    #pragma unroll
    for (int i = 0; i < SCAN_NB; ++i)
        if (i < b) boff += blocksum[t * SCAN_NB + i];
    int* o = offs + t * (NN + 1);
    int* cur = cursor + t * NN;
    if (b == SCAN_NB - 1 && threadIdx.x == 0)
        o[NN] = boff + blocksum[t * SCAN_NB + SCAN_NB - 1];   // = EE
    const int base = b * 2048 + threadIdx.x * 8;
    #pragma unroll
    for (int j = 0; j < 8; ++j) {
        const int i = base + j;
        if (i < NN) {
            const int val = o[i] + boff;
            o[i] = val;
            cur[i] = val;
        }
    }
}

// ---------------- scatter, int4-vectorized ----------------
__global__ __launch_bounds__(256) void scatter4_k(const int* __restrict__ src0,
                                                  const int* __restrict__ dst0,
                                                  const int* __restrict__ src1,
                                                  const int* __restrict__ dst1,
                                                  int* __restrict__ cursor,
                                                  int* __restrict__ csr_src) {
    const int i = blockIdx.x * 256 + threadIdx.x;   // i < EE/4
    if (i >= EE / 4) return;
    const int t = blockIdx.y;
    const int4 s = reinterpret_cast<const int4*>(t ? src1 : src0)[i];
    const int4 d = reinterpret_cast<const int4*>(t ? dst1 : dst0)[i];
    int* cur = cursor + t * NN;
    int* cs = csr_src + t * EE;
    cs[atomicAdd(&cur[d.x], 1)] = s.x;
    cs[atomicAdd(&cur[d.y], 1)] = s.y;
    cs[atomicAdd(&cur[d.z], 1)] = s.z;
    cs[atomicAdd(&cur[d.w], 1)] = s.w;
}

// ---------------- pull aggregate v10: predicated loads + optional fused final linear --------
// block = 4 waves = 2 nodes x 2 etypes. lane = sub*16 + cg. Depth-3 index / depth-2 data
// pipeline; invalid lanes issue NO loads (exec-masked) -- kills the clamped-prefetch
// over-fetch (~1.67x for mean degree 10). fuse_out=1 (layer 3): block computes
// out[n][0:16] = h @ Wout + bout directly from the f32 h row in LDS.
__global__ __launch_bounds__(256) void pull_agg10_k(const int* __restrict__ csr_src,
                                                    const int* __restrict__ offs,
                                                    const float* __restrict__ el,
                                                    const float* __restrict__ er,
                                                    const f16* __restrict__ feat,
                                                    const float* __restrict__ b0,
                                                    const float* __restrict__ b1,
                                                    f16* __restrict__ out, int relu,
                                                    const float* __restrict__ Wout,
                                                    const float* __restrict__ bout,
                                                    float* __restrict__ outf, int fuse_out) {
    __shared__ float xb[2][2][128];             // [node-parity][etype][col]
    const int w = threadIdx.x >> 6, lane = threadIdx.x & 63;
    const int p = w >> 1, t = w & 1;
    const int n = blockIdx.x * 2 + p;           // NN even
    const int sub = lane >> 4;                  // edge slot within quad (0..3)
    const int cg = lane & 15;                   // col group
    const int h = cg >> 2;                      // head
    const int c0 = cg * 8;

    const int* so = offs + t * (NN + 1);
    const int e0 = so[n], e1 = so[n + 1];

    float s = 0.f;
    float x[8];
    #pragma unroll
    for (int j = 0; j < 8; ++j) x[j] = 0.f;

    if (e0 < e1) {
        const int* cs = csr_src + t * EE;
        const float* elt = el + t * NN * HH;
        const float erh = er[t * NN * HH + n * HH + h];
        const f16* ft = feat + (size_t)t * NN * 128;

        // prologue (all loads exec-mask predicated)
        bool v0 = (e0 + sub) < e1;
        bool v1 = (e0 + 4 + sub) < e1;
        bool v2 = (e0 + 8 + sub) < e1;
        int si_0 = 0, si_1 = 0, si_2 = 0;
        if (v0) si_0 = cs[e0 + sub];
        if (v1) si_1 = cs[e0 + 4 + sub];
        if (v2) si_2 = cs[e0 + 8 + sub];
        float lv_0 = 0.f, lv_1 = 0.f;
        f16x8 fr_0 = {}, fr_1 = {};
        if (v0) {
            lv_0 = elt[si_0 * HH + h];
            fr_0 = *reinterpret_cast<const f16x8*>(ft + (size_t)si_0 * 128 + c0);
        }
        if (v1) {
            lv_1 = elt[si_1 * HH + h];
            fr_1 = *reinterpret_cast<const f16x8*>(ft + (size_t)si_1 * 128 + c0);
        }

        for (int eb = e0; eb < e1; eb += 4) {
            const bool v3 = (eb + 12 + sub) < e1;       // index for quad q+3
            int si_3 = 0;
            if (v3) si_3 = cs[eb + 12 + sub];
            float lv_2 = 0.f;                            // data for quad q+2
            f16x8 fr_2 = {};
            if (v2) {
                lv_2 = elt[si_2 * HH + h];
                fr_2 = *reinterpret_cast<const f16x8*>(ft + (size_t)si_2 * 128 + c0);
            }
            float v = lv_0 + erh;                        // compute quad q
            v = (v >= 0.f) ? v : v * SLOPE;
            float ex = __expf(v);
            ex = v0 ? ex : 0.f;
            s += ex;
            #pragma unroll
            for (int j = 0; j < 8; ++j) x[j] = fmaf(ex, (float)fr_0[j], x[j]);
            // rotate
            lv_0 = lv_1; fr_0 = fr_1; v0 = v1;
            lv_1 = lv_2; fr_1 = fr_2; v1 = v2;
            si_2 = si_3; v2 = v3;
        }
    }

    // combine across edge-sub lanes (bits 4,5)
    s += __shfl_xor(s, 16); s += __shfl_xor(s, 32);
    #pragma unroll
    for (int j = 0; j < 8; ++j) {
        x[j] += __shfl_xor(x[j], 16);
        x[j] += __shfl_xor(x[j], 32);
    }
    const float inv = (s > 0.f) ? 1.f / s : 0.f;    // isolated node -> 0, matches ref
    if (sub == 0) {
        float4 v0s = make_float4(x[0] * inv, x[1] * inv, x[2] * inv, x[3] * inv);
        float4 v1s = make_float4(x[4] * inv, x[5] * inv, x[6] * inv, x[7] * inv);
        *reinterpret_cast<float4*>(&xb[p][t][c0]) = v0s;
        *reinterpret_cast<float4*>(&xb[p][t][c0 + 4]) = v1s;
    }
    __syncthreads();
    if (t == 0) {
        const int c = lane * 2;
        float a0 = xb[p][0][c] + xb[p][1][c] + b0[c] + b1[c];
        float a1 = xb[p][0][c + 1] + xb[p][1][c + 1] + b0[c + 1] + b1[c + 1];
        if (!fuse_out) {
            if (relu) { a0 = fmaxf(a0, 0.f); a1 = fmaxf(a1, 0.f); }
            union { f16 h2[2]; float f; } o;
            o.h2[0] = (f16)a0; o.h2[1] = (f16)a1;
            *reinterpret_cast<float*>(out + (size_t)n * 128 + c) = o.f;
        } else {
            xb[p][0][c] = a0;                   // deposit f32 h row for the mini-GEMM
            xb[p][0][c + 1] = a1;
        }
    }
    if (fuse_out) {
        __syncthreads();
        // tid = p2*128 + c*8 + j : 2 nodes x 16 outputs x 8 partial-sum lanes
        const int p2 = threadIdx.x >> 7;
        const int c = (threadIdx.x >> 3) & 15;
        const int j = threadIdx.x & 7;
        float acc = 0.f;
        #pragma unroll
        for (int k = 0; k < 16; ++k) {
            const int kk = j * 16 + k;
            acc = fmaf(xb[p2][0][kk], Wout[kk * 16 + c], acc);
        }
        acc += __shfl_xor(acc, 1); acc += __shfl_xor(acc, 2); acc += __shfl_xor(acc, 4);
        if (j == 0) outf[(size_t)(blockIdx.x * 2 + p2) * 16 + c] = acc + bout[c];
    }
}

extern "C" void kernel_launch(void* const* d_in, const int* in_sizes, int n_in,
                              void* d_out, int out_size, void* d_ws, size_t ws_size,
                              hipStream_t stream) {
    (void)in_sizes; (void)n_in; (void)out_size; (void)ws_size;
    const float* x = (const float*)d_in[0];
    const int* src0 = (const int*)d_in[1];
    const int* dst0 = (const int*)d_in[2];
    const int* src1 = (const int*)d_in[3];
    const int* dst1 = (const int*)d_in[4];
    const float* W[3]  = {(const float*)d_in[5], (const float*)d_in[9],  (const float*)d_in[13]};
    const float* al[3] = {(const float*)d_in[6], (const float*)d_in[10], (const float*)d_in[14]};
    const float* ar[3] = {(const float*)d_in[7], (const float*)d_in[11], (const float*)d_in[15]};
    const float* bb[3] = {(const float*)d_in[8], (const float*)d_in[12], (const float*)d_in[16]};
    const float* Wout = (const float*)d_in[17];
    const float* bout = (const float*)d_in[18];
    float* outp = (float*)d_out;

    char* pb = (char*)d_ws;
    f16* feat   = (f16*)pb;    pb += (size_t)2 * NN * 128 * 2;   // [2][NN][128] fp16
    f16* hbuf   = (f16*)pb;    pb += (size_t)NN * 128 * 2;
    float* el   = (float*)pb;  pb += (size_t)2 * NN * HH * 4;
    float* er   = (float*)pb;  pb += (size_t)2 * NN * HH * 4;
    int* deg    = (int*)pb;    pb += (size_t)2 * NN * 4;
    int* cursor = (int*)pb;    pb += (size_t)2 * NN * 4;
    int* offs   = (int*)pb;    pb += (size_t)2 * (NN + 1) * 4;
    int* bsum   = (int*)pb;    pb += (size_t)2 * SCAN_NB * 4;
    f16* Wh     = (f16*)pb;    pb += (size_t)3 * 2 * 128 * 128 * 2;
    int* csr    = (int*)pb;    pb += (size_t)2 * EE * 4;

    // ---- setup: W convert + deg zero (1 kernel), then CSR build ----
    prep_k<<<dim3(8, 2, 4), 256, 0, stream>>>(W[0], W[1], W[2], Wh, (int4*)deg);
    hist4_k<<<dim3((EE / 4 + 255) / 256, 2), 256, 0, stream>>>(dst0, dst1, deg);
    scan1_k<<<dim3(SCAN_NB, 2), 256, 0, stream>>>(deg, offs, bsum);
    scan3b_k<<<dim3(SCAN_NB, 2), 256, 0, stream>>>(offs, bsum, cursor);
    scatter4_k<<<dim3((EE / 4 + 255) / 256, 2), 256, 0, stream>>>(src0, dst0, src1, dst1,
                                                                  cursor, csr);

    // ---- 3 GAT layers (layer 3 fuses the final 128->16 linear) ----
    const f16* hin = hbuf;
    for (int l = 0; l < 3; ++l) {
        gemm_mfma<<<938, 256, 0, stream>>>(
            hin, x, (l == 0) ? 1 : 0, Wh + l * 2 * 16384, al[l], ar[l], feat, el, er);
        pull_agg10_k<<<NN / 2, 256, 0, stream>>>(csr, offs, el, er, feat,
                                                 bb[l], bb[l] + 128, hbuf, (l < 2) ? 1 : 0,
                                                 Wout, bout, outp, (l == 2) ? 1 : 0);
        hin = hbuf;
    }
}

// Round 17
// 261.908 us; speedup vs baseline: 1.0225x; 1.0225x over previous
//
#include <hip/hip_runtime.h>

#define NN 30000
#define EE 300000
#define HH 4
#define SLOPE 0.2f
#define SCAN_NB 15        // ceil(30000 / 2048)

typedef _Float16 f16;
typedef f16 f16x8 __attribute__((ext_vector_type(8)));
typedef float f32x4 __attribute__((ext_vector_type(4)));

// ---------------- prep: z<3 -> W layer-z f16 transpose; z==3 -> zero deg ----------------
__global__ __launch_bounds__(256) void prep_k(const float* __restrict__ W0,
                                              const float* __restrict__ W1,
                                              const float* __restrict__ W2,
                                              f16* __restrict__ Wh,
                                              int4* __restrict__ deg4) {
    const int z = blockIdx.z;
    if (z == 3) {
        const int base = (blockIdx.y * 8 + blockIdx.x) * 256 + threadIdx.x;  // 4096 threads
        for (int j = base; j < 2 * NN / 4; j += 4096) deg4[j] = make_int4(0, 0, 0, 0);
        return;
    }
    const int t = blockIdx.y;
    const float* W = (z == 0) ? W0 : ((z == 1) ? W1 : W2);
    f16* Whl = Wh + (size_t)z * 2 * 16384;
    const int i0 = blockIdx.x * 2048;
    #pragma unroll
    for (int j = 0; j < 8; ++j) {
        const int i = i0 + threadIdx.x + j * 256;     // i = k*128 + col (coalesced read)
        const int k = i >> 7, col = i & 127;
        Whl[t * 16384 + col * 128 + k] = (f16)W[t * 16384 + i];
    }
}

// ---------------- MFMA GEMM: feat16[t][n][:] = A @ W[t], fused el/er epilogue ----------------
// 1D grid 938: bx = blockIdx.x>>1, et = blockIdx.x&1 (adjacent etype blocks share A via L2).
#define APAD 136
__global__ __launch_bounds__(256) void gemm_mfma(const f16* __restrict__ Ah,
                                                 const float* __restrict__ Af,
                                                 const int use_f32,
                                                 const f16* __restrict__ Whbase,
                                                 const float* __restrict__ albase,
                                                 const float* __restrict__ arbase,
                                                 f16* __restrict__ featbase,
                                                 float* __restrict__ elbase,
                                                 float* __restrict__ erbase) {
    __shared__ f16 Bsl[128 * APAD];
    const int bx = blockIdx.x >> 1;
    const int et = blockIdx.x & 1;
    const f16* Wh = Whbase + et * 16384;
    f16* feat = featbase + (size_t)et * NN * 128;
    const int row0 = bx * 64;
    const int t = threadIdx.x;

    #pragma unroll
    for (int j = 0; j < 8; ++j) {
        const int idx = t + j * 256;            // idx = col*16 + k16
        const int col = idx >> 4, k16 = idx & 15;
        *reinterpret_cast<float4*>(&Bsl[col * APAD + k16 * 8]) =
            *reinterpret_cast<const float4*>(Wh + col * 128 + k16 * 8);
    }
    __syncthreads();

    const int w = t >> 6, lane = t & 63;
    const int r = lane & 15, g = lane >> 4;
    const int mb = w * 16;
    const int rowa = min(row0 + mb + r, NN - 1);
    f32x4 acc[8];
    #pragma unroll
    for (int nt = 0; nt < 8; ++nt) acc[nt] = (f32x4){0.f, 0.f, 0.f, 0.f};

    #pragma unroll
    for (int ks = 0; ks < 4; ++ks) {
        f16x8 av;
        if (use_f32) {
            const float4 a0 =
                *reinterpret_cast<const float4*>(Af + (size_t)rowa * 128 + ks * 32 + g * 8);
            const float4 a1 =
                *reinterpret_cast<const float4*>(Af + (size_t)rowa * 128 + ks * 32 + g * 8 + 4);
            av[0] = (f16)a0.x; av[1] = (f16)a0.y; av[2] = (f16)a0.z; av[3] = (f16)a0.w;
            av[4] = (f16)a1.x; av[5] = (f16)a1.y; av[6] = (f16)a1.z; av[7] = (f16)a1.w;
        } else {
            av = *reinterpret_cast<const f16x8*>(Ah + (size_t)rowa * 128 + ks * 32 + g * 8);
        }
        #pragma unroll
        for (int nt = 0; nt < 8; ++nt) {
            const f16x8 bv =
                *reinterpret_cast<const f16x8*>(&Bsl[(nt * 16 + r) * APAD + ks * 32 + g * 8]);
            acc[nt] = __builtin_amdgcn_mfma_f32_16x16x32_f16(av, bv, acc[nt], 0, 0, 0);
        }
    }

    float alv[8], arv[8];
    #pragma unroll
    for (int nt = 0; nt < 8; ++nt) {            // col = nt*16 + r
        alv[nt] = albase[et * 128 + nt * 16 + r];
        arv[nt] = arbase[et * 128 + nt * 16 + r];
    }
    #pragma unroll
    for (int p = 0; p < 4; ++p) {
        const int row = row0 + mb + g * 4 + p;
        const bool ok = row < NN;
        if (ok) {
            #pragma unroll
            for (int nt = 0; nt < 8; ++nt)
                feat[(size_t)row * 128 + nt * 16 + r] = (f16)acc[nt][p];
        }
        #pragma unroll
        for (int h = 0; h < 4; ++h) {
            float pl = fmaf(acc[2 * h][p], alv[2 * h], acc[2 * h + 1][p] * alv[2 * h + 1]);
            float pr = fmaf(acc[2 * h][p], arv[2 * h], acc[2 * h + 1][p] * arv[2 * h + 1]);
            pl += __shfl_xor(pl, 1); pl += __shfl_xor(pl, 2);
            pl += __shfl_xor(pl, 4); pl += __shfl_xor(pl, 8);
            pr += __shfl_xor(pr, 1); pr += __shfl_xor(pr, 2);
            pr += __shfl_xor(pr, 4); pr += __shfl_xor(pr, 8);
            if (ok && r == 0) {
                elbase[et * NN * HH + row * HH + h] = pl;
                erbase[et * NN * HH + row * HH + h] = pr;
            }
        }
    }
}

// ---------------- CSR build: histogram, int4-vectorized ----------------
__global__ __launch_bounds__(256) void hist4_k(const int* __restrict__ dst0,
                                               const int* __restrict__ dst1,
                                               int* __restrict__ deg) {
    const int i = blockIdx.x * 256 + threadIdx.x;   // i < EE/4
    if (i >= EE / 4) return;
    const int t = blockIdx.y;
    const int4 d = reinterpret_cast<const int4*>(t ? dst1 : dst0)[i];
    int* dg = deg + t * NN;
    atomicAdd(&dg[d.x], 1);
    atomicAdd(&dg[d.y], 1);
    atomicAdd(&dg[d.z], 1);
    atomicAdd(&dg[d.w], 1);
}

// ---------------- multi-block exclusive scan, phase 1 ----------------
__global__ __launch_bounds__(256) void scan1_k(const int* __restrict__ deg,
                                               int* __restrict__ offs,
                                               int* __restrict__ blocksum) {
    const int t = blockIdx.y, b = blockIdx.x;
    const int* d = deg + t * NN;
    int* o = offs + t * (NN + 1);
    const int base = b * 2048 + threadIdx.x * 8;
    int v[8];
    int s = 0;
    #pragma unroll
    for (int j = 0; j < 8; ++j) {
        const int i = base + j;
        v[j] = (i < NN) ? d[i] : 0;
        s += v[j];
    }
    __shared__ int buf[256];
    buf[threadIdx.x] = s;
    __syncthreads();
    #pragma unroll
    for (int ofs = 1; ofs < 256; ofs <<= 1) {
        const int add = (threadIdx.x >= (unsigned)ofs) ? buf[threadIdx.x - ofs] : 0;
        __syncthreads();
        buf[threadIdx.x] += add;
        __syncthreads();
    }
    int run = buf[threadIdx.x] - s;
    #pragma unroll
    for (int j = 0; j < 8; ++j) {
        const int i = base + j;
        if (i < NN) o[i] = run;
        run += v[j];
    }
    if (threadIdx.x == 255) blocksum[t * SCAN_NB + b] = buf[255];
}

// ---------------- scan phase 2+3 merged ----------------
__global__ __launch_bounds__(256) void scan3b_k(int* __restrict__ offs,
                                                const int* __restrict__ blocksum,
                                                int* __restrict__ cursor) {
    const int t = blockIdx.y, b = blockIdx.x;
    int boff = 0;
    #pragma unroll
    for (int i = 0; i < SCAN_NB; ++i)
        if (i < b) boff += blocksum[t * SCAN_NB + i];
    int* o = offs + t * (NN + 1);
    int* cur = cursor + t * NN;
    if (b == SCAN_NB - 1 && threadIdx.x == 0)
        o[NN] = boff + blocksum[t * SCAN_NB + SCAN_NB - 1];   // = EE
    const int base = b * 2048 + threadIdx.x * 8;
    #pragma unroll
    for (int j = 0; j < 8; ++j) {
        const int i = base + j;
        if (i < NN) {
            const int val = o[i] + boff;
            o[i] = val;
            cur[i] = val;
        }
    }
}

// ---------------- scatter, int4-vectorized ----------------
__global__ __launch_bounds__(256) void scatter4_k(const int* __restrict__ src0,
                                                  const int* __restrict__ dst0,
                                                  const int* __restrict__ src1,
                                                  const int* __restrict__ dst1,
                                                  int* __restrict__ cursor,
                                                  int* __restrict__ csr_src) {
    const int i = blockIdx.x * 256 + threadIdx.x;   // i < EE/4
    if (i >= EE / 4) return;
    const int t = blockIdx.y;
    const int4 s = reinterpret_cast<const int4*>(t ? src1 : src0)[i];
    const int4 d = reinterpret_cast<const int4*>(t ? dst1 : dst0)[i];
    int* cur = cursor + t * NN;
    int* cs = csr_src + t * EE;
    cs[atomicAdd(&cur[d.x], 1)] = s.x;
    cs[atomicAdd(&cur[d.y], 1)] = s.y;
    cs[atomicAdd(&cur[d.z], 1)] = s.z;
    cs[atomicAdd(&cur[d.w], 1)] = s.w;
}

// ---------------- pull aggregate v11: round-15 clamped pipeline + fused final linear --------
// block = 4 waves = 2 nodes x 2 etypes. lane = sub*16 + cg. Depth-3 index / depth-2 data
// pipeline with CLAMPED prefetch (round-16 lesson: branch-predicated loads destroy the
// pipeline; clamped loads are cache-hits and cost ~nothing). fuse_out=1 (layer 3): block
// computes out[n][0:16] = h @ Wout + bout directly from the f32 h row in LDS.
__global__ __launch_bounds__(256) void pull_agg11_k(const int* __restrict__ csr_src,
                                                    const int* __restrict__ offs,
                                                    const float* __restrict__ el,
                                                    const float* __restrict__ er,
                                                    const f16* __restrict__ feat,
                                                    const float* __restrict__ b0,
                                                    const float* __restrict__ b1,
                                                    f16* __restrict__ out, int relu,
                                                    const float* __restrict__ Wout,
                                                    const float* __restrict__ bout,
                                                    float* __restrict__ outf, int fuse_out) {
    __shared__ float xb[2][2][128];             // [node-parity][etype][col]
    const int w = threadIdx.x >> 6, lane = threadIdx.x & 63;
    const int p = w >> 1, t = w & 1;
    const int n = blockIdx.x * 2 + p;           // NN even
    const int sub = lane >> 4;                  // edge slot within quad (0..3)
    const int cg = lane & 15;                   // col group
    const int h = cg >> 2;                      // head
    const int c0 = cg * 8;

    const int* so = offs + t * (NN + 1);
    const int e0 = so[n], e1 = so[n + 1];

    float s = 0.f;
    float x[8];
    #pragma unroll
    for (int j = 0; j < 8; ++j) x[j] = 0.f;

    if (e0 < e1) {
        const int* cs = csr_src + t * EE;
        const float* elt = el + t * NN * HH;
        const float erh = er[t * NN * HH + n * HH + h];
        const f16* ft = feat + (size_t)t * NN * 128;
        const int elast = e1 - 1;

        // prologue: quads 0,1 index+data; quad 2 index (all clamped, cache-hot)
        int si_0 = cs[min(e0 + sub, elast)];
        int si_1 = cs[min(e0 + 4 + sub, elast)];
        int si_2 = cs[min(e0 + 8 + sub, elast)];
        float lv_0 = elt[si_0 * HH + h];
        f16x8 fr_0 = *reinterpret_cast<const f16x8*>(ft + (size_t)si_0 * 128 + c0);
        float lv_1 = elt[si_1 * HH + h];
        f16x8 fr_1 = *reinterpret_cast<const f16x8*>(ft + (size_t)si_1 * 128 + c0);

        for (int eb = e0; eb < e1; eb += 4) {
            const int si_3 = cs[min(eb + 12 + sub, elast)];       // index for quad q+3
            const float lv_2 = elt[si_2 * HH + h];                // data for quad q+2
            const f16x8 fr_2 = *reinterpret_cast<const f16x8*>(ft + (size_t)si_2 * 128 + c0);
            float v = lv_0 + erh;                                  // compute quad q
            v = (v >= 0.f) ? v : v * SLOPE;
            float ex = __expf(v);
            ex = (eb + sub < e1) ? ex : 0.f;
            s += ex;
            #pragma unroll
            for (int j = 0; j < 8; ++j) x[j] = fmaf(ex, (float)fr_0[j], x[j]);
            // rotate
            lv_0 = lv_1; fr_0 = fr_1;
            lv_1 = lv_2; fr_1 = fr_2;
            si_2 = si_3;
        }
    }

    // combine across edge-sub lanes (bits 4,5)
    s += __shfl_xor(s, 16); s += __shfl_xor(s, 32);
    #pragma unroll
    for (int j = 0; j < 8; ++j) {
        x[j] += __shfl_xor(x[j], 16);
        x[j] += __shfl_xor(x[j], 32);
    }
    const float inv = (s > 0.f) ? 1.f / s : 0.f;    // isolated node -> 0, matches ref
    if (sub == 0) {
        float4 v0 = make_float4(x[0] * inv, x[1] * inv, x[2] * inv, x[3] * inv);
        float4 v1 = make_float4(x[4] * inv, x[5] * inv, x[6] * inv, x[7] * inv);
        *reinterpret_cast<float4*>(&xb[p][t][c0]) = v0;
        *reinterpret_cast<float4*>(&xb[p][t][c0 + 4]) = v1;
    }
    __syncthreads();
    if (t == 0) {
        const int c = lane * 2;
        float a0 = xb[p][0][c] + xb[p][1][c] + b0[c] + b1[c];
        float a1 = xb[p][0][c + 1] + xb[p][1][c + 1] + b0[c + 1] + b1[c + 1];
        if (!fuse_out) {
            if (relu) { a0 = fmaxf(a0, 0.f); a1 = fmaxf(a1, 0.f); }
            union { f16 h2[2]; float f; } o;
            o.h2[0] = (f16)a0; o.h2[1] = (f16)a1;
            *reinterpret_cast<float*>(out + (size_t)n * 128 + c) = o.f;
        } else {
            xb[p][0][c] = a0;                   // deposit f32 h row for the mini-GEMM
            xb[p][0][c + 1] = a1;
        }
    }
    if (fuse_out) {
        __syncthreads();
        // tid = p2*128 + c*8 + j : 2 nodes x 16 outputs x 8 partial-sum lanes.
        // kk = k*8 + j -> per-k lane addresses consecutive (conflict-free banks).
        const int p2 = threadIdx.x >> 7;
        const int c = (threadIdx.x >> 3) & 15;
        const int j = threadIdx.x & 7;
        float acc = 0.f;
        #pragma unroll
        for (int k = 0; k < 16; ++k) {
            const int kk = k * 8 + j;
            acc = fmaf(xb[p2][0][kk], Wout[kk * 16 + c], acc);
        }
        acc += __shfl_xor(acc, 1); acc += __shfl_xor(acc, 2); acc += __shfl_xor(acc, 4);
        if (j == 0) outf[(size_t)(blockIdx.x * 2 + p2) * 16 + c] = acc + bout[c];
    }
}

extern "C" void kernel_launch(void* const* d_in, const int* in_sizes, int n_in,
                              void* d_out, int out_size, void* d_ws, size_t ws_size,
                              hipStream_t stream) {
    (void)in_sizes; (void)n_in; (void)out_size; (void)ws_size;
    const float* x = (const float*)d_in[0];
    const int* src0 = (const int*)d_in[1];
    const int* dst0 = (const int*)d_in[2];
    const int* src1 = (const int*)d_in[3];
    const int* dst1 = (const int*)d_in[4];
    const float* W[3]  = {(const float*)d_in[5], (const float*)d_in[9],  (const float*)d_in[13]};
    const float* al[3] = {(const float*)d_in[6], (const float*)d_in[10], (const float*)d_in[14]};
    const float* ar[3] = {(const float*)d_in[7], (const float*)d_in[11], (const float*)d_in[15]};
    const float* bb[3] = {(const float*)d_in[8], (const float*)d_in[12], (const float*)d_in[16]};
    const float* Wout = (const float*)d_in[17];
    const float* bout = (const float*)d_in[18];
    float* outp = (float*)d_out;

    char* pb = (char*)d_ws;
    f16* feat   = (f16*)pb;    pb += (size_t)2 * NN * 128 * 2;   // [2][NN][128] fp16
    f16* hbuf   = (f16*)pb;    pb += (size_t)NN * 128 * 2;
    float* el   = (float*)pb;  pb += (size_t)2 * NN * HH * 4;
    float* er   = (float*)pb;  pb += (size_t)2 * NN * HH * 4;
    int* deg    = (int*)pb;    pb += (size_t)2 * NN * 4;
    int* cursor = (int*)pb;    pb += (size_t)2 * NN * 4;
    int* offs   = (int*)pb;    pb += (size_t)2 * (NN + 1) * 4;
    int* bsum   = (int*)pb;    pb += (size_t)2 * SCAN_NB * 4;
    f16* Wh     = (f16*)pb;    pb += (size_t)3 * 2 * 128 * 128 * 2;
    int* csr    = (int*)pb;    pb += (size_t)2 * EE * 4;

    // ---- setup: W convert + deg zero (1 kernel), then CSR build ----
    prep_k<<<dim3(8, 2, 4), 256, 0, stream>>>(W[0], W[1], W[2], Wh, (int4*)deg);
    hist4_k<<<dim3((EE / 4 + 255) / 256, 2), 256, 0, stream>>>(dst0, dst1, deg);
    scan1_k<<<dim3(SCAN_NB, 2), 256, 0, stream>>>(deg, offs, bsum);
    scan3b_k<<<dim3(SCAN_NB, 2), 256, 0, stream>>>(offs, bsum, cursor);
    scatter4_k<<<dim3((EE / 4 + 255) / 256, 2), 256, 0, stream>>>(src0, dst0, src1, dst1,
                                                                  cursor, csr);

    // ---- 3 GAT layers (layer 3 fuses the final 128->16 linear) ----
    const f16* hin = hbuf;
    for (int l = 0; l < 3; ++l) {
        gemm_mfma<<<938, 256, 0, stream>>>(
            hin, x, (l == 0) ? 1 : 0, Wh + l * 2 * 16384, al[l], ar[l], feat, el, er);
        pull_agg11_k<<<NN / 2, 256, 0, stream>>>(csr, offs, el, er, feat,
                                                 bb[l], bb[l] + 128, hbuf, (l < 2) ? 1 : 0,
                                                 Wout, bout, outp, (l == 2) ? 1 : 0);
        hin = hbuf;
    }
}

// Round 18
// 227.477 us; speedup vs baseline: 1.1773x; 1.1514x over previous
//
#include <hip/hip_runtime.h>

#define NN 30000
#define EE 300000
#define HH 4
#define SLOPE 0.2f
#define SCAN_NB 15        // ceil(30000 / 2048)

typedef _Float16 f16;
typedef f16 f16x8 __attribute__((ext_vector_type(8)));
typedef float f32x4 __attribute__((ext_vector_type(4)));

// ---------------- prep: z<3 -> W layer-z f16 transpose; z==3 -> zero deg ----------------
__global__ __launch_bounds__(256) void prep_k(const float* __restrict__ W0,
                                              const float* __restrict__ W1,
                                              const float* __restrict__ W2,
                                              f16* __restrict__ Wh,
                                              int4* __restrict__ deg4) {
    const int z = blockIdx.z;
    if (z == 3) {
        const int base = (blockIdx.y * 8 + blockIdx.x) * 256 + threadIdx.x;  // 4096 threads
        for (int j = base; j < 2 * NN / 4; j += 4096) deg4[j] = make_int4(0, 0, 0, 0);
        return;
    }
    const int t = blockIdx.y;
    const float* W = (z == 0) ? W0 : ((z == 1) ? W1 : W2);
    f16* Whl = Wh + (size_t)z * 2 * 16384;
    const int i0 = blockIdx.x * 2048;
    #pragma unroll
    for (int j = 0; j < 8; ++j) {
        const int i = i0 + threadIdx.x + j * 256;     // i = k*128 + col (coalesced read)
        const int k = i >> 7, col = i & 127;
        Whl[t * 16384 + col * 128 + k] = (f16)W[t * 16384 + i];
    }
}

// ---------------- MFMA GEMM: feat16[t][n][:] = A @ W[t], fused el/er epilogue ----------------
// 1D grid 938: bx = blockIdx.x>>1, et = blockIdx.x&1 (adjacent etype blocks share A via L2).
#define APAD 136
__global__ __launch_bounds__(256) void gemm_mfma(const f16* __restrict__ Ah,
                                                 const float* __restrict__ Af,
                                                 const int use_f32,
                                                 const f16* __restrict__ Whbase,
                                                 const float* __restrict__ albase,
                                                 const float* __restrict__ arbase,
                                                 f16* __restrict__ featbase,
                                                 float* __restrict__ elbase,
                                                 float* __restrict__ erbase) {
    __shared__ f16 Bsl[128 * APAD];
    const int bx = blockIdx.x >> 1;
    const int et = blockIdx.x & 1;
    const f16* Wh = Whbase + et * 16384;
    f16* feat = featbase + (size_t)et * NN * 128;
    const int row0 = bx * 64;
    const int t = threadIdx.x;

    #pragma unroll
    for (int j = 0; j < 8; ++j) {
        const int idx = t + j * 256;            // idx = col*16 + k16
        const int col = idx >> 4, k16 = idx & 15;
        *reinterpret_cast<float4*>(&Bsl[col * APAD + k16 * 8]) =
            *reinterpret_cast<const float4*>(Wh + col * 128 + k16 * 8);
    }
    __syncthreads();

    const int w = t >> 6, lane = t & 63;
    const int r = lane & 15, g = lane >> 4;
    const int mb = w * 16;
    const int rowa = min(row0 + mb + r, NN - 1);
    f32x4 acc[8];
    #pragma unroll
    for (int nt = 0; nt < 8; ++nt) acc[nt] = (f32x4){0.f, 0.f, 0.f, 0.f};

    #pragma unroll
    for (int ks = 0; ks < 4; ++ks) {
        f16x8 av;
        if (use_f32) {
            const float4 a0 =
                *reinterpret_cast<const float4*>(Af + (size_t)rowa * 128 + ks * 32 + g * 8);
            const float4 a1 =
                *reinterpret_cast<const float4*>(Af + (size_t)rowa * 128 + ks * 32 + g * 8 + 4);
            av[0] = (f16)a0.x; av[1] = (f16)a0.y; av[2] = (f16)a0.z; av[3] = (f16)a0.w;
            av[4] = (f16)a1.x; av[5] = (f16)a1.y; av[6] = (f16)a1.z; av[7] = (f16)a1.w;
        } else {
            av = *reinterpret_cast<const f16x8*>(Ah + (size_t)rowa * 128 + ks * 32 + g * 8);
        }
        #pragma unroll
        for (int nt = 0; nt < 8; ++nt) {
            const f16x8 bv =
                *reinterpret_cast<const f16x8*>(&Bsl[(nt * 16 + r) * APAD + ks * 32 + g * 8]);
            acc[nt] = __builtin_amdgcn_mfma_f32_16x16x32_f16(av, bv, acc[nt], 0, 0, 0);
        }
    }

    float alv[8], arv[8];
    #pragma unroll
    for (int nt = 0; nt < 8; ++nt) {            // col = nt*16 + r
        alv[nt] = albase[et * 128 + nt * 16 + r];
        arv[nt] = arbase[et * 128 + nt * 16 + r];
    }
    #pragma unroll
    for (int p = 0; p < 4; ++p) {
        const int row = row0 + mb + g * 4 + p;
        const bool ok = row < NN;
        if (ok) {
            #pragma unroll
            for (int nt = 0; nt < 8; ++nt)
                feat[(size_t)row * 128 + nt * 16 + r] = (f16)acc[nt][p];
        }
        #pragma unroll
        for (int h = 0; h < 4; ++h) {
            float pl = fmaf(acc[2 * h][p], alv[2 * h], acc[2 * h + 1][p] * alv[2 * h + 1]);
            float pr = fmaf(acc[2 * h][p], arv[2 * h], acc[2 * h + 1][p] * arv[2 * h + 1]);
            pl += __shfl_xor(pl, 1); pl += __shfl_xor(pl, 2);
            pl += __shfl_xor(pl, 4); pl += __shfl_xor(pl, 8);
            pr += __shfl_xor(pr, 1); pr += __shfl_xor(pr, 2);
            pr += __shfl_xor(pr, 4); pr += __shfl_xor(pr, 8);
            if (ok && r == 0) {
                elbase[et * NN * HH + row * HH + h] = pl;
                erbase[et * NN * HH + row * HH + h] = pr;
            }
        }
    }
}

// ---------------- CSR build: histogram, int4-vectorized ----------------
__global__ __launch_bounds__(256) void hist4_k(const int* __restrict__ dst0,
                                               const int* __restrict__ dst1,
                                               int* __restrict__ deg) {
    const int i = blockIdx.x * 256 + threadIdx.x;   // i < EE/4
    if (i >= EE / 4) return;
    const int t = blockIdx.y;
    const int4 d = reinterpret_cast<const int4*>(t ? dst1 : dst0)[i];
    int* dg = deg + t * NN;
    atomicAdd(&dg[d.x], 1);
    atomicAdd(&dg[d.y], 1);
    atomicAdd(&dg[d.z], 1);
    atomicAdd(&dg[d.w], 1);
}

// ---------------- multi-block exclusive scan, phase 1 ----------------
__global__ __launch_bounds__(256) void scan1_k(const int* __restrict__ deg,
                                               int* __restrict__ offs,
                                               int* __restrict__ blocksum) {
    const int t = blockIdx.y, b = blockIdx.x;
    const int* d = deg + t * NN;
    int* o = offs + t * (NN + 1);
    const int base = b * 2048 + threadIdx.x * 8;
    int v[8];
    int s = 0;
    #pragma unroll
    for (int j = 0; j < 8; ++j) {
        const int i = base + j;
        v[j] = (i < NN) ? d[i] : 0;
        s += v[j];
    }
    __shared__ int buf[256];
    buf[threadIdx.x] = s;
    __syncthreads();
    #pragma unroll
    for (int ofs = 1; ofs < 256; ofs <<= 1) {
        const int add = (threadIdx.x >= (unsigned)ofs) ? buf[threadIdx.x - ofs] : 0;
        __syncthreads();
        buf[threadIdx.x] += add;
        __syncthreads();
    }
    int run = buf[threadIdx.x] - s;
    #pragma unroll
    for (int j = 0; j < 8; ++j) {
        const int i = base + j;
        if (i < NN) o[i] = run;
        run += v[j];
    }
    if (threadIdx.x == 255) blocksum[t * SCAN_NB + b] = buf[255];
}

// ---------------- scan phase 2+3 merged ----------------
__global__ __launch_bounds__(256) void scan3b_k(int* __restrict__ offs,
                                                const int* __restrict__ blocksum,
                                                int* __restrict__ cursor) {
    const int t = blockIdx.y, b = blockIdx.x;
    int boff = 0;
    #pragma unroll
    for (int i = 0; i < SCAN_NB; ++i)
        if (i < b) boff += blocksum[t * SCAN_NB + i];
    int* o = offs + t * (NN + 1);
    int* cur = cursor + t * NN;
    if (b == SCAN_NB - 1 && threadIdx.x == 0)
        o[NN] = boff + blocksum[t * SCAN_NB + SCAN_NB - 1];   // = EE
    const int base = b * 2048 + threadIdx.x * 8;
    #pragma unroll
    for (int j = 0; j < 8; ++j) {
        const int i = base + j;
        if (i < NN) {
            const int val = o[i] + boff;
            o[i] = val;
            cur[i] = val;
        }
    }
}

// ---------------- scatter, int4-vectorized ----------------
__global__ __launch_bounds__(256) void scatter4_k(const int* __restrict__ src0,
                                                  const int* __restrict__ dst0,
                                                  const int* __restrict__ src1,
                                                  const int* __restrict__ dst1,
                                                  int* __restrict__ cursor,
                                                  int* __restrict__ csr_src) {
    const int i = blockIdx.x * 256 + threadIdx.x;   // i < EE/4
    if (i >= EE / 4) return;
    const int t = blockIdx.y;
    const int4 s = reinterpret_cast<const int4*>(t ? src1 : src0)[i];
    const int4 d = reinterpret_cast<const int4*>(t ? dst1 : dst0)[i];
    int* cur = cursor + t * NN;
    int* cs = csr_src + t * EE;
    cs[atomicAdd(&cur[d.x], 1)] = s.x;
    cs[atomicAdd(&cur[d.y], 1)] = s.y;
    cs[atomicAdd(&cur[d.z], 1)] = s.z;
    cs[atomicAdd(&cur[d.w], 1)] = s.w;
}

// ---------------- pull aggregate v12: depth-4 index / depth-3 data pipeline ----------------
// block = 4 waves = 2 nodes x 2 etypes. lane = sub*16 + cg. Mean degree = 10 -> ~2.5 quads:
// the depth-3 prologue issues essentially the whole segment's gathers before first compute.
// Clamped prefetch (round-16 lesson: clamps are cache-hot/free; branch-predication kills
// the pipeline). NO fused epilogue (round-17 lesson: it perturbs regalloc, -13us/dispatch).
__global__ __launch_bounds__(256) void pull_agg12_k(const int* __restrict__ csr_src,
                                                    const int* __restrict__ offs,
                                                    const float* __restrict__ el,
                                                    const float* __restrict__ er,
                                                    const f16* __restrict__ feat,
                                                    const float* __restrict__ b0,
                                                    const float* __restrict__ b1,
                                                    f16* __restrict__ out, int relu) {
    __shared__ float xb[2][2][128];             // [node-parity][etype][col], normalized
    const int w = threadIdx.x >> 6, lane = threadIdx.x & 63;
    const int p = w >> 1, t = w & 1;
    const int n = blockIdx.x * 2 + p;           // NN even
    const int sub = lane >> 4;                  // edge slot within quad (0..3)
    const int cg = lane & 15;                   // col group
    const int h = cg >> 2;                      // head
    const int c0 = cg * 8;

    const int* so = offs + t * (NN + 1);
    const int e0 = so[n], e1 = so[n + 1];

    float s = 0.f;
    float x[8];
    #pragma unroll
    for (int j = 0; j < 8; ++j) x[j] = 0.f;

    if (e0 < e1) {
        const int* cs = csr_src + t * EE;
        const float* elt = el + t * NN * HH;
        const float erh = er[t * NN * HH + n * HH + h];
        const f16* ft = feat + (size_t)t * NN * 128;
        const int elast = e1 - 1;

        // prologue: quads 0,1,2 index+data; quad 3 index (all clamped, cache-hot)
        int si_0 = cs[min(e0 + sub, elast)];
        int si_1 = cs[min(e0 + 4 + sub, elast)];
        int si_2 = cs[min(e0 + 8 + sub, elast)];
        int si_3 = cs[min(e0 + 12 + sub, elast)];
        float lv_0 = elt[si_0 * HH + h];
        f16x8 fr_0 = *reinterpret_cast<const f16x8*>(ft + (size_t)si_0 * 128 + c0);
        float lv_1 = elt[si_1 * HH + h];
        f16x8 fr_1 = *reinterpret_cast<const f16x8*>(ft + (size_t)si_1 * 128 + c0);
        float lv_2 = elt[si_2 * HH + h];
        f16x8 fr_2 = *reinterpret_cast<const f16x8*>(ft + (size_t)si_2 * 128 + c0);

        for (int eb = e0; eb < e1; eb += 4) {
            const int si_4 = cs[min(eb + 16 + sub, elast)];       // index for quad q+4
            const float lv_3 = elt[si_3 * HH + h];                // data for quad q+3
            const f16x8 fr_3 = *reinterpret_cast<const f16x8*>(ft + (size_t)si_3 * 128 + c0);
            float v = lv_0 + erh;                                  // compute quad q
            v = (v >= 0.f) ? v : v * SLOPE;
            float ex = __expf(v);
            ex = (eb + sub < e1) ? ex : 0.f;
            s += ex;
            #pragma unroll
            for (int j = 0; j < 8; ++j) x[j] = fmaf(ex, (float)fr_0[j], x[j]);
            // rotate
            lv_0 = lv_1; fr_0 = fr_1;
            lv_1 = lv_2; fr_1 = fr_2;
            lv_2 = lv_3; fr_2 = fr_3;
            si_3 = si_4;
        }
    }

    // combine across edge-sub lanes (bits 4,5)
    s += __shfl_xor(s, 16); s += __shfl_xor(s, 32);
    #pragma unroll
    for (int j = 0; j < 8; ++j) {
        x[j] += __shfl_xor(x[j], 16);
        x[j] += __shfl_xor(x[j], 32);
    }
    const float inv = (s > 0.f) ? 1.f / s : 0.f;    // isolated node -> 0, matches ref
    if (sub == 0) {
        float4 v0 = make_float4(x[0] * inv, x[1] * inv, x[2] * inv, x[3] * inv);
        float4 v1 = make_float4(x[4] * inv, x[5] * inv, x[6] * inv, x[7] * inv);
        *reinterpret_cast<float4*>(&xb[p][t][c0]) = v0;
        *reinterpret_cast<float4*>(&xb[p][t][c0 + 4]) = v1;
    }
    __syncthreads();
    if (t == 0) {
        const int c = lane * 2;
        float a0 = xb[p][0][c] + xb[p][1][c] + b0[c] + b1[c];
        float a1 = xb[p][0][c + 1] + xb[p][1][c + 1] + b0[c + 1] + b1[c + 1];
        if (relu) { a0 = fmaxf(a0, 0.f); a1 = fmaxf(a1, 0.f); }
        union { f16 h2[2]; float f; } o;
        o.h2[0] = (f16)a0; o.h2[1] = (f16)a1;
        *reinterpret_cast<float*>(out + (size_t)n * 128 + c) = o.f;
    }
}

// ---------------- final linear (f16 input) ----------------
__global__ __launch_bounds__(256) void out_gemm_k(const f16* __restrict__ A,
                                                  const float* __restrict__ W,
                                                  const float* __restrict__ bout,
                                                  float* __restrict__ out) {
    __shared__ float At[16][132];
    const int row0 = blockIdx.x * 16;   // NN % 16 == 0
    const int t = threadIdx.x;
    {
        const int r = t >> 4, c8 = t & 15;
        const f16x8 v = *reinterpret_cast<const f16x8*>(A + (size_t)(row0 + r) * 128 + c8 * 8);
        #pragma unroll
        for (int j = 0; j < 8; ++j) At[r][c8 * 8 + j] = (float)v[j];
    }
    __syncthreads();
    const int r = t >> 4, c = t & 15;
    float accv = 0.f;
    #pragma unroll 8
    for (int k = 0; k < 128; ++k) accv = fmaf(At[r][k], W[k * 16 + c], accv);
    out[(row0 + r) * 16 + c] = accv + bout[c];
}

extern "C" void kernel_launch(void* const* d_in, const int* in_sizes, int n_in,
                              void* d_out, int out_size, void* d_ws, size_t ws_size,
                              hipStream_t stream) {
    (void)in_sizes; (void)n_in; (void)out_size; (void)ws_size;
    const float* x = (const float*)d_in[0];
    const int* src0 = (const int*)d_in[1];
    const int* dst0 = (const int*)d_in[2];
    const int* src1 = (const int*)d_in[3];
    const int* dst1 = (const int*)d_in[4];
    const float* W[3]  = {(const float*)d_in[5], (const float*)d_in[9],  (const float*)d_in[13]};
    const float* al[3] = {(const float*)d_in[6], (const float*)d_in[10], (const float*)d_in[14]};
    const float* ar[3] = {(const float*)d_in[7], (const float*)d_in[11], (const float*)d_in[15]};
    const float* bb[3] = {(const float*)d_in[8], (const float*)d_in[12], (const float*)d_in[16]};
    const float* Wout = (const float*)d_in[17];
    const float* bout = (const float*)d_in[18];
    float* outp = (float*)d_out;

    char* pb = (char*)d_ws;
    f16* feat   = (f16*)pb;    pb += (size_t)2 * NN * 128 * 2;   // [2][NN][128] fp16
    f16* hbuf   = (f16*)pb;    pb += (size_t)NN * 128 * 2;
    float* el   = (float*)pb;  pb += (size_t)2 * NN * HH * 4;
    float* er   = (float*)pb;  pb += (size_t)2 * NN * HH * 4;
    int* deg    = (int*)pb;    pb += (size_t)2 * NN * 4;
    int* cursor = (int*)pb;    pb += (size_t)2 * NN * 4;
    int* offs   = (int*)pb;    pb += (size_t)2 * (NN + 1) * 4;
    int* bsum   = (int*)pb;    pb += (size_t)2 * SCAN_NB * 4;
    f16* Wh     = (f16*)pb;    pb += (size_t)3 * 2 * 128 * 128 * 2;
    int* csr    = (int*)pb;    pb += (size_t)2 * EE * 4;

    // ---- setup: W convert + deg zero (1 kernel), then CSR build ----
    prep_k<<<dim3(8, 2, 4), 256, 0, stream>>>(W[0], W[1], W[2], Wh, (int4*)deg);
    hist4_k<<<dim3((EE / 4 + 255) / 256, 2), 256, 0, stream>>>(dst0, dst1, deg);
    scan1_k<<<dim3(SCAN_NB, 2), 256, 0, stream>>>(deg, offs, bsum);
    scan3b_k<<<dim3(SCAN_NB, 2), 256, 0, stream>>>(offs, bsum, cursor);
    scatter4_k<<<dim3((EE / 4 + 255) / 256, 2), 256, 0, stream>>>(src0, dst0, src1, dst1,
                                                                  cursor, csr);

    // ---- 3 GAT layers ----
    const f16* hin = hbuf;
    for (int l = 0; l < 3; ++l) {
        gemm_mfma<<<938, 256, 0, stream>>>(
            hin, x, (l == 0) ? 1 : 0, Wh + l * 2 * 16384, al[l], ar[l], feat, el, er);
        pull_agg12_k<<<NN / 2, 256, 0, stream>>>(csr, offs, el, er, feat,
                                                 bb[l], bb[l] + 128, hbuf, (l < 2) ? 1 : 0);
        hin = hbuf;
    }
    out_gemm_k<<<NN / 16, 256, 0, stream>>>(hbuf, Wout, bout, outp);
}

// Round 19
// 223.997 us; speedup vs baseline: 1.1956x; 1.0155x over previous
//
#include <hip/hip_runtime.h>

#define NN 30000
#define EE 300000
#define HH 4
#define SLOPE 0.2f
#define SCAN_NB 15        // ceil(30000 / 2048)

typedef _Float16 f16;
typedef f16 f16x8 __attribute__((ext_vector_type(8)));
typedef float f32x4 __attribute__((ext_vector_type(4)));
typedef unsigned short u16;

// ---------------- prep: z<3 -> W layer-z f16 transpose; z==3 -> zero deg ----------------
__global__ __launch_bounds__(256) void prep_k(const float* __restrict__ W0,
                                              const float* __restrict__ W1,
                                              const float* __restrict__ W2,
                                              f16* __restrict__ Wh,
                                              int4* __restrict__ deg4) {
    const int z = blockIdx.z;
    if (z == 3) {
        const int base = (blockIdx.y * 8 + blockIdx.x) * 256 + threadIdx.x;  // 4096 threads
        for (int j = base; j < 2 * NN / 4; j += 4096) deg4[j] = make_int4(0, 0, 0, 0);
        return;
    }
    const int t = blockIdx.y;
    const float* W = (z == 0) ? W0 : ((z == 1) ? W1 : W2);
    f16* Whl = Wh + (size_t)z * 2 * 16384;
    const int i0 = blockIdx.x * 2048;
    #pragma unroll
    for (int j = 0; j < 8; ++j) {
        const int i = i0 + threadIdx.x + j * 256;     // i = k*128 + col (coalesced read)
        const int k = i >> 7, col = i & 127;
        Whl[t * 16384 + col * 128 + k] = (f16)W[t * 16384 + i];
    }
}

// ---------------- MFMA GEMM: feat16[t][n][:] = A @ W[t], fused el/er epilogue ----------------
// 1D grid 938: bx = blockIdx.x>>1, et = blockIdx.x&1 (adjacent etype blocks share A via L2).
#define APAD 136
__global__ __launch_bounds__(256) void gemm_mfma(const f16* __restrict__ Ah,
                                                 const float* __restrict__ Af,
                                                 const int use_f32,
                                                 const f16* __restrict__ Whbase,
                                                 const float* __restrict__ albase,
                                                 const float* __restrict__ arbase,
                                                 f16* __restrict__ featbase,
                                                 float* __restrict__ elbase,
                                                 float* __restrict__ erbase) {
    __shared__ f16 Bsl[128 * APAD];
    const int bx = blockIdx.x >> 1;
    const int et = blockIdx.x & 1;
    const f16* Wh = Whbase + et * 16384;
    f16* feat = featbase + (size_t)et * NN * 128;
    const int row0 = bx * 64;
    const int t = threadIdx.x;

    #pragma unroll
    for (int j = 0; j < 8; ++j) {
        const int idx = t + j * 256;            // idx = col*16 + k16
        const int col = idx >> 4, k16 = idx & 15;
        *reinterpret_cast<float4*>(&Bsl[col * APAD + k16 * 8]) =
            *reinterpret_cast<const float4*>(Wh + col * 128 + k16 * 8);
    }
    __syncthreads();

    const int w = t >> 6, lane = t & 63;
    const int r = lane & 15, g = lane >> 4;
    const int mb = w * 16;
    const int rowa = min(row0 + mb + r, NN - 1);
    f32x4 acc[8];
    #pragma unroll
    for (int nt = 0; nt < 8; ++nt) acc[nt] = (f32x4){0.f, 0.f, 0.f, 0.f};

    #pragma unroll
    for (int ks = 0; ks < 4; ++ks) {
        f16x8 av;
        if (use_f32) {
            const float4 a0 =
                *reinterpret_cast<const float4*>(Af + (size_t)rowa * 128 + ks * 32 + g * 8);
            const float4 a1 =
                *reinterpret_cast<const float4*>(Af + (size_t)rowa * 128 + ks * 32 + g * 8 + 4);
            av[0] = (f16)a0.x; av[1] = (f16)a0.y; av[2] = (f16)a0.z; av[3] = (f16)a0.w;
            av[4] = (f16)a1.x; av[5] = (f16)a1.y; av[6] = (f16)a1.z; av[7] = (f16)a1.w;
        } else {
            av = *reinterpret_cast<const f16x8*>(Ah + (size_t)rowa * 128 + ks * 32 + g * 8);
        }
        #pragma unroll
        for (int nt = 0; nt < 8; ++nt) {
            const f16x8 bv =
                *reinterpret_cast<const f16x8*>(&Bsl[(nt * 16 + r) * APAD + ks * 32 + g * 8]);
            acc[nt] = __builtin_amdgcn_mfma_f32_16x16x32_f16(av, bv, acc[nt], 0, 0, 0);
        }
    }

    float alv[8], arv[8];
    #pragma unroll
    for (int nt = 0; nt < 8; ++nt) {            // col = nt*16 + r
        alv[nt] = albase[et * 128 + nt * 16 + r];
        arv[nt] = arbase[et * 128 + nt * 16 + r];
    }
    #pragma unroll
    for (int p = 0; p < 4; ++p) {
        const int row = row0 + mb + g * 4 + p;
        const bool ok = row < NN;
        if (ok) {
            #pragma unroll
            for (int nt = 0; nt < 8; ++nt)
                feat[(size_t)row * 128 + nt * 16 + r] = (f16)acc[nt][p];
        }
        #pragma unroll
        for (int h = 0; h < 4; ++h) {
            float pl = fmaf(acc[2 * h][p], alv[2 * h], acc[2 * h + 1][p] * alv[2 * h + 1]);
            float pr = fmaf(acc[2 * h][p], arv[2 * h], acc[2 * h + 1][p] * arv[2 * h + 1]);
            pl += __shfl_xor(pl, 1); pl += __shfl_xor(pl, 2);
            pl += __shfl_xor(pl, 4); pl += __shfl_xor(pl, 8);
            pr += __shfl_xor(pr, 1); pr += __shfl_xor(pr, 2);
            pr += __shfl_xor(pr, 4); pr += __shfl_xor(pr, 8);
            if (ok && r == 0) {
                elbase[et * NN * HH + row * HH + h] = pl;
                erbase[et * NN * HH + row * HH + h] = pr;
            }
        }
    }
}

// ---------------- CSR build: histogram, int4-vectorized ----------------
__global__ __launch_bounds__(256) void hist4_k(const int* __restrict__ dst0,
                                               const int* __restrict__ dst1,
                                               int* __restrict__ deg) {
    const int i = blockIdx.x * 256 + threadIdx.x;   // i < EE/4
    if (i >= EE / 4) return;
    const int t = blockIdx.y;
    const int4 d = reinterpret_cast<const int4*>(t ? dst1 : dst0)[i];
    int* dg = deg + t * NN;
    atomicAdd(&dg[d.x], 1);
    atomicAdd(&dg[d.y], 1);
    atomicAdd(&dg[d.z], 1);
    atomicAdd(&dg[d.w], 1);
}

// ---------------- multi-block exclusive scan, phase 1 ----------------
__global__ __launch_bounds__(256) void scan1_k(const int* __restrict__ deg,
                                               int* __restrict__ offs,
                                               int* __restrict__ blocksum) {
    const int t = blockIdx.y, b = blockIdx.x;
    const int* d = deg + t * NN;
    int* o = offs + t * (NN + 1);
    const int base = b * 2048 + threadIdx.x * 8;
    int v[8];
    int s = 0;
    #pragma unroll
    for (int j = 0; j < 8; ++j) {
        const int i = base + j;
        v[j] = (i < NN) ? d[i] : 0;
        s += v[j];
    }
    __shared__ int buf[256];
    buf[threadIdx.x] = s;
    __syncthreads();
    #pragma unroll
    for (int ofs = 1; ofs < 256; ofs <<= 1) {
        const int add = (threadIdx.x >= (unsigned)ofs) ? buf[threadIdx.x - ofs] : 0;
        __syncthreads();
        buf[threadIdx.x] += add;
        __syncthreads();
    }
    int run = buf[threadIdx.x] - s;
    #pragma unroll
    for (int j = 0; j < 8; ++j) {
        const int i = base + j;
        if (i < NN) o[i] = run;
        run += v[j];
    }
    if (threadIdx.x == 255) blocksum[t * SCAN_NB + b] = buf[255];
}

// ---------------- scan phase 2+3 merged ----------------
__global__ __launch_bounds__(256) void scan3b_k(int* __restrict__ offs,
                                                const int* __restrict__ blocksum,
                                                int* __restrict__ cursor) {
    const int t = blockIdx.y, b = blockIdx.x;
    int boff = 0;
    #pragma unroll
    for (int i = 0; i < SCAN_NB; ++i)
        if (i < b) boff += blocksum[t * SCAN_NB + i];
    int* o = offs + t * (NN + 1);
    int* cur = cursor + t * NN;
    if (b == SCAN_NB - 1 && threadIdx.x == 0)
        o[NN] = boff + blocksum[t * SCAN_NB + SCAN_NB - 1];   // = EE
    const int base = b * 2048 + threadIdx.x * 8;
    #pragma unroll
    for (int j = 0; j < 8; ++j) {
        const int i = base + j;
        if (i < NN) {
            const int val = o[i] + boff;
            o[i] = val;
            cur[i] = val;
        }
    }
}

// ---------------- scatter, int4-vectorized, ushort CSR payload ----------------
// NN < 2^16 -> src fits in ushort: halves the CSR line footprint (18.7K -> 9.4K lines),
// cutting the random-write line-eviction traffic that dominates this kernel.
__global__ __launch_bounds__(256) void scatter4_k(const int* __restrict__ src0,
                                                  const int* __restrict__ dst0,
                                                  const int* __restrict__ src1,
                                                  const int* __restrict__ dst1,
                                                  int* __restrict__ cursor,
                                                  u16* __restrict__ csr_src) {
    const int i = blockIdx.x * 256 + threadIdx.x;   // i < EE/4
    if (i >= EE / 4) return;
    const int t = blockIdx.y;
    const int4 s = reinterpret_cast<const int4*>(t ? src1 : src0)[i];
    const int4 d = reinterpret_cast<const int4*>(t ? dst1 : dst0)[i];
    int* cur = cursor + t * NN;
    u16* cs = csr_src + t * EE;
    cs[atomicAdd(&cur[d.x], 1)] = (u16)s.x;
    cs[atomicAdd(&cur[d.y], 1)] = (u16)s.y;
    cs[atomicAdd(&cur[d.z], 1)] = (u16)s.z;
    cs[atomicAdd(&cur[d.w], 1)] = (u16)s.w;
}

// ---------------- pull aggregate v12u: depth-4 index / depth-3 data pipeline (u16 csr) ------
// block = 4 waves = 2 nodes x 2 etypes. lane = sub*16 + cg. Clamped prefetch (round-16
// lesson: clamps are cache-hot/free; branch-predication kills the pipeline). No fused
// epilogue (round-17 lesson: perturbs regalloc).
__global__ __launch_bounds__(256) void pull_agg12_k(const u16* __restrict__ csr_src,
                                                    const int* __restrict__ offs,
                                                    const float* __restrict__ el,
                                                    const float* __restrict__ er,
                                                    const f16* __restrict__ feat,
                                                    const float* __restrict__ b0,
                                                    const float* __restrict__ b1,
                                                    f16* __restrict__ out, int relu) {
    __shared__ float xb[2][2][128];             // [node-parity][etype][col], normalized
    const int w = threadIdx.x >> 6, lane = threadIdx.x & 63;
    const int p = w >> 1, t = w & 1;
    const int n = blockIdx.x * 2 + p;           // NN even
    const int sub = lane >> 4;                  // edge slot within quad (0..3)
    const int cg = lane & 15;                   // col group
    const int h = cg >> 2;                      // head
    const int c0 = cg * 8;

    const int* so = offs + t * (NN + 1);
    const int e0 = so[n], e1 = so[n + 1];

    float s = 0.f;
    float x[8];
    #pragma unroll
    for (int j = 0; j < 8; ++j) x[j] = 0.f;

    if (e0 < e1) {
        const u16* cs = csr_src + t * EE;
        const float* elt = el + t * NN * HH;
        const float erh = er[t * NN * HH + n * HH + h];
        const f16* ft = feat + (size_t)t * NN * 128;
        const int elast = e1 - 1;

        // prologue: quads 0,1,2 index+data; quad 3 index (all clamped, cache-hot)
        int si_0 = cs[min(e0 + sub, elast)];
        int si_1 = cs[min(e0 + 4 + sub, elast)];
        int si_2 = cs[min(e0 + 8 + sub, elast)];
        int si_3 = cs[min(e0 + 12 + sub, elast)];
        float lv_0 = elt[si_0 * HH + h];
        f16x8 fr_0 = *reinterpret_cast<const f16x8*>(ft + (size_t)si_0 * 128 + c0);
        float lv_1 = elt[si_1 * HH + h];
        f16x8 fr_1 = *reinterpret_cast<const f16x8*>(ft + (size_t)si_1 * 128 + c0);
        float lv_2 = elt[si_2 * HH + h];
        f16x8 fr_2 = *reinterpret_cast<const f16x8*>(ft + (size_t)si_2 * 128 + c0);

        for (int eb = e0; eb < e1; eb += 4) {
            const int si_4 = cs[min(eb + 16 + sub, elast)];       // index for quad q+4
            const float lv_3 = elt[si_3 * HH + h];                // data for quad q+3
            const f16x8 fr_3 = *reinterpret_cast<const f16x8*>(ft + (size_t)si_3 * 128 + c0);
            float v = lv_0 + erh;                                  // compute quad q
            v = (v >= 0.f) ? v : v * SLOPE;
            float ex = __expf(v);
            ex = (eb + sub < e1) ? ex : 0.f;
            s += ex;
            #pragma unroll
            for (int j = 0; j < 8; ++j) x[j] = fmaf(ex, (float)fr_0[j], x[j]);
            // rotate
            lv_0 = lv_1; fr_0 = fr_1;
            lv_1 = lv_2; fr_1 = fr_2;
            lv_2 = lv_3; fr_2 = fr_3;
            si_3 = si_4;
        }
    }

    // combine across edge-sub lanes (bits 4,5)
    s += __shfl_xor(s, 16); s += __shfl_xor(s, 32);
    #pragma unroll
    for (int j = 0; j < 8; ++j) {
        x[j] += __shfl_xor(x[j], 16);
        x[j] += __shfl_xor(x[j], 32);
    }
    const float inv = (s > 0.f) ? 1.f / s : 0.f;    // isolated node -> 0, matches ref
    if (sub == 0) {
        float4 v0 = make_float4(x[0] * inv, x[1] * inv, x[2] * inv, x[3] * inv);
        float4 v1 = make_float4(x[4] * inv, x[5] * inv, x[6] * inv, x[7] * inv);
        *reinterpret_cast<float4*>(&xb[p][t][c0]) = v0;
        *reinterpret_cast<float4*>(&xb[p][t][c0 + 4]) = v1;
    }
    __syncthreads();
    if (t == 0) {
        const int c = lane * 2;
        float a0 = xb[p][0][c] + xb[p][1][c] + b0[c] + b1[c];
        float a1 = xb[p][0][c + 1] + xb[p][1][c + 1] + b0[c + 1] + b1[c + 1];
        if (relu) { a0 = fmaxf(a0, 0.f); a1 = fmaxf(a1, 0.f); }
        union { f16 h2[2]; float f; } o;
        o.h2[0] = (f16)a0; o.h2[1] = (f16)a1;
        *reinterpret_cast<float*>(out + (size_t)n * 128 + c) = o.f;
    }
}

// ---------------- final linear (f16 input) ----------------
__global__ __launch_bounds__(256) void out_gemm_k(const f16* __restrict__ A,
                                                  const float* __restrict__ W,
                                                  const float* __restrict__ bout,
                                                  float* __restrict__ out) {
    __shared__ float At[16][132];
    const int row0 = blockIdx.x * 16;   // NN % 16 == 0
    const int t = threadIdx.x;
    {
        const int r = t >> 4, c8 = t & 15;
        const f16x8 v = *reinterpret_cast<const f16x8*>(A + (size_t)(row0 + r) * 128 + c8 * 8);
        #pragma unroll
        for (int j = 0; j < 8; ++j) At[r][c8 * 8 + j] = (float)v[j];
    }
    __syncthreads();
    const int r = t >> 4, c = t & 15;
    float accv = 0.f;
    #pragma unroll 8
    for (int k = 0; k < 128; ++k) accv = fmaf(At[r][k], W[k * 16 + c], accv);
    out[(row0 + r) * 16 + c] = accv + bout[c];
}

extern "C" void kernel_launch(void* const* d_in, const int* in_sizes, int n_in,
                              void* d_out, int out_size, void* d_ws, size_t ws_size,
                              hipStream_t stream) {
    (void)in_sizes; (void)n_in; (void)out_size; (void)ws_size;
    const float* x = (const float*)d_in[0];
    const int* src0 = (const int*)d_in[1];
    const int* dst0 = (const int*)d_in[2];
    const int* src1 = (const int*)d_in[3];
    const int* dst1 = (const int*)d_in[4];
    const float* W[3]  = {(const float*)d_in[5], (const float*)d_in[9],  (const float*)d_in[13]};
    const float* al[3] = {(const float*)d_in[6], (const float*)d_in[10], (const float*)d_in[14]};
    const float* ar[3] = {(const float*)d_in[7], (const float*)d_in[11], (const float*)d_in[15]};
    const float* bb[3] = {(const float*)d_in[8], (const float*)d_in[12], (const float*)d_in[16]};
    const float* Wout = (const float*)d_in[17];
    const float* bout = (const float*)d_in[18];
    float* outp = (float*)d_out;

    char* pb = (char*)d_ws;
    f16* feat   = (f16*)pb;    pb += (size_t)2 * NN * 128 * 2;   // [2][NN][128] fp16
    f16* hbuf   = (f16*)pb;    pb += (size_t)NN * 128 * 2;
    float* el   = (float*)pb;  pb += (size_t)2 * NN * HH * 4;
    float* er   = (float*)pb;  pb += (size_t)2 * NN * HH * 4;
    int* deg    = (int*)pb;    pb += (size_t)2 * NN * 4;
    int* cursor = (int*)pb;    pb += (size_t)2 * NN * 4;
    int* offs   = (int*)pb;    pb += (size_t)2 * (NN + 1) * 4;
    int* bsum   = (int*)pb;    pb += (size_t)2 * SCAN_NB * 4;
    f16* Wh     = (f16*)pb;    pb += (size_t)3 * 2 * 128 * 128 * 2;
    u16* csr    = (u16*)pb;    pb += (size_t)2 * EE * 2;

    // ---- setup: W convert + deg zero (1 kernel), then CSR build ----
    prep_k<<<dim3(8, 2, 4), 256, 0, stream>>>(W[0], W[1], W[2], Wh, (int4*)deg);
    hist4_k<<<dim3((EE / 4 + 255) / 256, 2), 256, 0, stream>>>(dst0, dst1, deg);
    scan1_k<<<dim3(SCAN_NB, 2), 256, 0, stream>>>(deg, offs, bsum);
    scan3b_k<<<dim3(SCAN_NB, 2), 256, 0, stream>>>(offs, bsum, cursor);
    scatter4_k<<<dim3((EE / 4 + 255) / 256, 2), 256, 0, stream>>>(src0, dst0, src1, dst1,
                                                                  cursor, csr);

    // ---- 3 GAT layers ----
    const f16* hin = hbuf;
    for (int l = 0; l < 3; ++l) {
        gemm_mfma<<<938, 256, 0, stream>>>(
            hin, x, (l == 0) ? 1 : 0, Wh + l * 2 * 16384, al[l], ar[l], feat, el, er);
        pull_agg12_k<<<NN / 2, 256, 0, stream>>>(csr, offs, el, er, feat,
                                                 bb[l], bb[l] + 128, hbuf, (l < 2) ? 1 : 0);
        hin = hbuf;
    }
    out_gemm_k<<<NN / 16, 256, 0, stream>>>(hbuf, Wout, bout, outp);
}

// Round 20
// 221.508 us; speedup vs baseline: 1.2090x; 1.0112x over previous
//
#include <hip/hip_runtime.h>

#define NN 30000
#define EE 300000
#define HH 4
#define SLOPE 0.2f
#define SCAN_NB 15        // ceil(30000 / 2048)
#define SCB 293           // ceil(EE/4 / 256) scatter blocks per etype

typedef _Float16 f16;
typedef f16 f16x8 __attribute__((ext_vector_type(8)));
typedef float f32x4 __attribute__((ext_vector_type(4)));
typedef unsigned short u16;

// ---------------- prep: z<3 -> W layer-z f16 transpose; z==3 -> zero deg ----------------
__global__ __launch_bounds__(256) void prep_k(const float* __restrict__ W0,
                                              const float* __restrict__ W1,
                                              const float* __restrict__ W2,
                                              f16* __restrict__ Wh,
                                              int4* __restrict__ deg4) {
    const int z = blockIdx.z;
    if (z == 3) {
        const int base = (blockIdx.y * 8 + blockIdx.x) * 256 + threadIdx.x;  // 4096 threads
        for (int j = base; j < 2 * NN / 4; j += 4096) deg4[j] = make_int4(0, 0, 0, 0);
        return;
    }
    const int t = blockIdx.y;
    const float* W = (z == 0) ? W0 : ((z == 1) ? W1 : W2);
    f16* Whl = Wh + (size_t)z * 2 * 16384;
    const int i0 = blockIdx.x * 2048;
    #pragma unroll
    for (int j = 0; j < 8; ++j) {
        const int i = i0 + threadIdx.x + j * 256;     // i = k*128 + col (coalesced read)
        const int k = i >> 7, col = i & 127;
        Whl[t * 16384 + col * 128 + k] = (f16)W[t * 16384 + i];
    }
}

// ---------------- MFMA GEMM (layers 2,3): feat16[t][n][:] = Ah @ W[t], fused el/er ----------
// 1D grid 938: bx = blockIdx.x>>1, et = blockIdx.x&1 (adjacent etype blocks share A via L2).
#define APAD 136
__global__ __launch_bounds__(256) void gemm_mfma(const f16* __restrict__ Ah,
                                                 const float* __restrict__ Af,
                                                 const int use_f32,
                                                 const f16* __restrict__ Whbase,
                                                 const float* __restrict__ albase,
                                                 const float* __restrict__ arbase,
                                                 f16* __restrict__ featbase,
                                                 float* __restrict__ elbase,
                                                 float* __restrict__ erbase) {
    __shared__ f16 Bsl[128 * APAD];
    const int bx = blockIdx.x >> 1;
    const int et = blockIdx.x & 1;
    const f16* Wh = Whbase + et * 16384;
    f16* feat = featbase + (size_t)et * NN * 128;
    const int row0 = bx * 64;
    const int t = threadIdx.x;

    #pragma unroll
    for (int j = 0; j < 8; ++j) {
        const int idx = t + j * 256;            // idx = col*16 + k16
        const int col = idx >> 4, k16 = idx & 15;
        *reinterpret_cast<float4*>(&Bsl[col * APAD + k16 * 8]) =
            *reinterpret_cast<const float4*>(Wh + col * 128 + k16 * 8);
    }
    __syncthreads();

    const int w = t >> 6, lane = t & 63;
    const int r = lane & 15, g = lane >> 4;
    const int mb = w * 16;
    const int rowa = min(row0 + mb + r, NN - 1);
    f32x4 acc[8];
    #pragma unroll
    for (int nt = 0; nt < 8; ++nt) acc[nt] = (f32x4){0.f, 0.f, 0.f, 0.f};

    #pragma unroll
    for (int ks = 0; ks < 4; ++ks) {
        f16x8 av;
        if (use_f32) {
            const float4 a0 =
                *reinterpret_cast<const float4*>(Af + (size_t)rowa * 128 + ks * 32 + g * 8);
            const float4 a1 =
                *reinterpret_cast<const float4*>(Af + (size_t)rowa * 128 + ks * 32 + g * 8 + 4);
            av[0] = (f16)a0.x; av[1] = (f16)a0.y; av[2] = (f16)a0.z; av[3] = (f16)a0.w;
            av[4] = (f16)a1.x; av[5] = (f16)a1.y; av[6] = (f16)a1.z; av[7] = (f16)a1.w;
        } else {
            av = *reinterpret_cast<const f16x8*>(Ah + (size_t)rowa * 128 + ks * 32 + g * 8);
        }
        #pragma unroll
        for (int nt = 0; nt < 8; ++nt) {
            const f16x8 bv =
                *reinterpret_cast<const f16x8*>(&Bsl[(nt * 16 + r) * APAD + ks * 32 + g * 8]);
            acc[nt] = __builtin_amdgcn_mfma_f32_16x16x32_f16(av, bv, acc[nt], 0, 0, 0);
        }
    }

    float alv[8], arv[8];
    #pragma unroll
    for (int nt = 0; nt < 8; ++nt) {            // col = nt*16 + r
        alv[nt] = albase[et * 128 + nt * 16 + r];
        arv[nt] = arbase[et * 128 + nt * 16 + r];
    }
    #pragma unroll
    for (int p = 0; p < 4; ++p) {
        const int row = row0 + mb + g * 4 + p;
        const bool ok = row < NN;
        if (ok) {
            #pragma unroll
            for (int nt = 0; nt < 8; ++nt)
                feat[(size_t)row * 128 + nt * 16 + r] = (f16)acc[nt][p];
        }
        #pragma unroll
        for (int h = 0; h < 4; ++h) {
            float pl = fmaf(acc[2 * h][p], alv[2 * h], acc[2 * h + 1][p] * alv[2 * h + 1]);
            float pr = fmaf(acc[2 * h][p], arv[2 * h], acc[2 * h + 1][p] * arv[2 * h + 1]);
            pl += __shfl_xor(pl, 1); pl += __shfl_xor(pl, 2);
            pl += __shfl_xor(pl, 4); pl += __shfl_xor(pl, 8);
            pr += __shfl_xor(pr, 1); pr += __shfl_xor(pr, 2);
            pr += __shfl_xor(pr, 4); pr += __shfl_xor(pr, 8);
            if (ok && r == 0) {
                elbase[et * NN * HH + row * HH + h] = pl;
                erbase[et * NN * HH + row * HH + h] = pr;
            }
        }
    }
}

// ---------------- merged: scatter (blocks 0..2*SCB-1) || layer-1 gemm (rest) --------------
// Uniform per-block branch (prep_k pattern) -> no intra-block regalloc interference.
// scatter runs at 19.6% occupancy (atomic-bound); gemm-1 rides in its idle slots for free.
__global__ __launch_bounds__(256) void gemm1_scatter_k(const float* __restrict__ Af,
                                                       const f16* __restrict__ Whbase,
                                                       const float* __restrict__ albase,
                                                       const float* __restrict__ arbase,
                                                       f16* __restrict__ featbase,
                                                       float* __restrict__ elbase,
                                                       float* __restrict__ erbase,
                                                       const int* __restrict__ src0,
                                                       const int* __restrict__ dst0,
                                                       const int* __restrict__ src1,
                                                       const int* __restrict__ dst1,
                                                       int* __restrict__ cursor,
                                                       u16* __restrict__ csr_src) {
    __shared__ f16 Bsl[128 * APAD];
    if (blockIdx.x < 2 * SCB) {
        // ---- scatter part (int4-vectorized, ushort CSR payload) ----
        const int t = (blockIdx.x >= SCB) ? 1 : 0;
        const int i = (blockIdx.x - t * SCB) * 256 + threadIdx.x;
        if (i < EE / 4) {
            const int4 s = reinterpret_cast<const int4*>(t ? src1 : src0)[i];
            const int4 d = reinterpret_cast<const int4*>(t ? dst1 : dst0)[i];
            int* cur = cursor + t * NN;
            u16* cs = csr_src + t * EE;
            cs[atomicAdd(&cur[d.x], 1)] = (u16)s.x;
            cs[atomicAdd(&cur[d.y], 1)] = (u16)s.y;
            cs[atomicAdd(&cur[d.z], 1)] = (u16)s.z;
            cs[atomicAdd(&cur[d.w], 1)] = (u16)s.w;
        }
        return;
    }
    // ---- layer-1 gemm part (f32 A path hardcoded) ----
    const int bxg = blockIdx.x - 2 * SCB;
    const int bx = bxg >> 1;
    const int et = bxg & 1;
    const f16* Wh = Whbase + et * 16384;
    f16* feat = featbase + (size_t)et * NN * 128;
    const int row0 = bx * 64;
    const int t = threadIdx.x;

    #pragma unroll
    for (int j = 0; j < 8; ++j) {
        const int idx = t + j * 256;            // idx = col*16 + k16
        const int col = idx >> 4, k16 = idx & 15;
        *reinterpret_cast<float4*>(&Bsl[col * APAD + k16 * 8]) =
            *reinterpret_cast<const float4*>(Wh + col * 128 + k16 * 8);
    }
    __syncthreads();

    const int w = t >> 6, lane = t & 63;
    const int r = lane & 15, g = lane >> 4;
    const int mb = w * 16;
    const int rowa = min(row0 + mb + r, NN - 1);
    f32x4 acc[8];
    #pragma unroll
    for (int nt = 0; nt < 8; ++nt) acc[nt] = (f32x4){0.f, 0.f, 0.f, 0.f};

    #pragma unroll
    for (int ks = 0; ks < 4; ++ks) {
        f16x8 av;
        {
            const float4 a0 =
                *reinterpret_cast<const float4*>(Af + (size_t)rowa * 128 + ks * 32 + g * 8);
            const float4 a1 =
                *reinterpret_cast<const float4*>(Af + (size_t)rowa * 128 + ks * 32 + g * 8 + 4);
            av[0] = (f16)a0.x; av[1] = (f16)a0.y; av[2] = (f16)a0.z; av[3] = (f16)a0.w;
            av[4] = (f16)a1.x; av[5] = (f16)a1.y; av[6] = (f16)a1.z; av[7] = (f16)a1.w;
        }
        #pragma unroll
        for (int nt = 0; nt < 8; ++nt) {
            const f16x8 bv =
                *reinterpret_cast<const f16x8*>(&Bsl[(nt * 16 + r) * APAD + ks * 32 + g * 8]);
            acc[nt] = __builtin_amdgcn_mfma_f32_16x16x32_f16(av, bv, acc[nt], 0, 0, 0);
        }
    }

    float alv[8], arv[8];
    #pragma unroll
    for (int nt = 0; nt < 8; ++nt) {            // col = nt*16 + r
        alv[nt] = albase[et * 128 + nt * 16 + r];
        arv[nt] = arbase[et * 128 + nt * 16 + r];
    }
    #pragma unroll
    for (int p = 0; p < 4; ++p) {
        const int row = row0 + mb + g * 4 + p;
        const bool ok = row < NN;
        if (ok) {
            #pragma unroll
            for (int nt = 0; nt < 8; ++nt)
                feat[(size_t)row * 128 + nt * 16 + r] = (f16)acc[nt][p];
        }
        #pragma unroll
        for (int h = 0; h < 4; ++h) {
            float pl = fmaf(acc[2 * h][p], alv[2 * h], acc[2 * h + 1][p] * alv[2 * h + 1]);
            float pr = fmaf(acc[2 * h][p], arv[2 * h], acc[2 * h + 1][p] * arv[2 * h + 1]);
            pl += __shfl_xor(pl, 1); pl += __shfl_xor(pl, 2);
            pl += __shfl_xor(pl, 4); pl += __shfl_xor(pl, 8);
            pr += __shfl_xor(pr, 1); pr += __shfl_xor(pr, 2);
            pr += __shfl_xor(pr, 4); pr += __shfl_xor(pr, 8);
            if (ok && r == 0) {
                elbase[et * NN * HH + row * HH + h] = pl;
                erbase[et * NN * HH + row * HH + h] = pr;
            }
        }
    }
}

// ---------------- CSR build: histogram, int4-vectorized ----------------
__global__ __launch_bounds__(256) void hist4_k(const int* __restrict__ dst0,
                                               const int* __restrict__ dst1,
                                               int* __restrict__ deg) {
    const int i = blockIdx.x * 256 + threadIdx.x;   // i < EE/4
    if (i >= EE / 4) return;
    const int t = blockIdx.y;
    const int4 d = reinterpret_cast<const int4*>(t ? dst1 : dst0)[i];
    int* dg = deg + t * NN;
    atomicAdd(&dg[d.x], 1);
    atomicAdd(&dg[d.y], 1);
    atomicAdd(&dg[d.z], 1);
    atomicAdd(&dg[d.w], 1);
}

// ---------------- multi-block exclusive scan, phase 1 ----------------
__global__ __launch_bounds__(256) void scan1_k(const int* __restrict__ deg,
                                               int* __restrict__ offs,
                                               int* __restrict__ blocksum) {
    const int t = blockIdx.y, b = blockIdx.x;
    const int* d = deg + t * NN;
    int* o = offs + t * (NN + 1);
    const int base = b * 2048 + threadIdx.x * 8;
    int v[8];
    int s = 0;
    #pragma unroll
    for (int j = 0; j < 8; ++j) {
        const int i = base + j;
        v[j] = (i < NN) ? d[i] : 0;
        s += v[j];
    }
    __shared__ int buf[256];
    buf[threadIdx.x] = s;
    __syncthreads();
    #pragma unroll
    for (int ofs = 1; ofs < 256; ofs <<= 1) {
        const int add = (threadIdx.x >= (unsigned)ofs) ? buf[threadIdx.x - ofs] : 0;
        __syncthreads();
        buf[threadIdx.x] += add;
        __syncthreads();
    }
    int run = buf[threadIdx.x] - s;
    #pragma unroll
    for (int j = 0; j < 8; ++j) {
        const int i = base + j;
        if (i < NN) o[i] = run;
        run += v[j];
    }
    if (threadIdx.x == 255) blocksum[t * SCAN_NB + b] = buf[255];
}

// ---------------- scan phase 2+3 merged ----------------
__global__ __launch_bounds__(256) void scan3b_k(int* __restrict__ offs,
                                                const int* __restrict__ blocksum,
                                                int* __restrict__ cursor) {
    const int t = blockIdx.y, b = blockIdx.x;
    int boff = 0;
    #pragma unroll
    for (int i = 0; i < SCAN_NB; ++i)
        if (i < b) boff += blocksum[t * SCAN_NB + i];
    int* o = offs + t * (NN + 1);
    int* cur = cursor + t * NN;
    if (b == SCAN_NB - 1 && threadIdx.x == 0)
        o[NN] = boff + blocksum[t * SCAN_NB + SCAN_NB - 1];   // = EE
    const int base = b * 2048 + threadIdx.x * 8;
    #pragma unroll
    for (int j = 0; j < 8; ++j) {
        const int i = base + j;
        if (i < NN) {
            const int val = o[i] + boff;
            o[i] = val;
            cur[i] = val;
        }
    }
}

// ---------------- pull aggregate v12u: depth-4 index / depth-3 data pipeline (u16 csr) ------
// block = 4 waves = 2 nodes x 2 etypes. lane = sub*16 + cg. Clamped prefetch (round-16
// lesson: clamps are cache-hot/free; branch-predication kills the pipeline). No fused
// epilogue (round-17 lesson: perturbs regalloc).
__global__ __launch_bounds__(256) void pull_agg12_k(const u16* __restrict__ csr_src,
                                                    const int* __restrict__ offs,
                                                    const float* __restrict__ el,
                                                    const float* __restrict__ er,
                                                    const f16* __restrict__ feat,
                                                    const float* __restrict__ b0,
                                                    const float* __restrict__ b1,
                                                    f16* __restrict__ out, int relu) {
    __shared__ float xb[2][2][128];             // [node-parity][etype][col], normalized
    const int w = threadIdx.x >> 6, lane = threadIdx.x & 63;
    const int p = w >> 1, t = w & 1;
    const int n = blockIdx.x * 2 + p;           // NN even
    const int sub = lane >> 4;                  // edge slot within quad (0..3)
    const int cg = lane & 15;                   // col group
    const int h = cg >> 2;                      // head
    const int c0 = cg * 8;

    const int* so = offs + t * (NN + 1);
    const int e0 = so[n], e1 = so[n + 1];

    float s = 0.f;
    float x[8];
    #pragma unroll
    for (int j = 0; j < 8; ++j) x[j] = 0.f;

    if (e0 < e1) {
        const u16* cs = csr_src + t * EE;
        const float* elt = el + t * NN * HH;
        const float erh = er[t * NN * HH + n * HH + h];
        const f16* ft = feat + (size_t)t * NN * 128;
        const int elast = e1 - 1;

        // prologue: quads 0,1,2 index+data; quad 3 index (all clamped, cache-hot)
        int si_0 = cs[min(e0 + sub, elast)];
        int si_1 = cs[min(e0 + 4 + sub, elast)];
        int si_2 = cs[min(e0 + 8 + sub, elast)];
        int si_3 = cs[min(e0 + 12 + sub, elast)];
        float lv_0 = elt[si_0 * HH + h];
        f16x8 fr_0 = *reinterpret_cast<const f16x8*>(ft + (size_t)si_0 * 128 + c0);
        float lv_1 = elt[si_1 * HH + h];
        f16x8 fr_1 = *reinterpret_cast<const f16x8*>(ft + (size_t)si_1 * 128 + c0);
        float lv_2 = elt[si_2 * HH + h];
        f16x8 fr_2 = *reinterpret_cast<const f16x8*>(ft + (size_t)si_2 * 128 + c0);

        for (int eb = e0; eb < e1; eb += 4) {
            const int si_4 = cs[min(eb + 16 + sub, elast)];       // index for quad q+4
            const float lv_3 = elt[si_3 * HH + h];                // data for quad q+3
            const f16x8 fr_3 = *reinterpret_cast<const f16x8*>(ft + (size_t)si_3 * 128 + c0);
            float v = lv_0 + erh;                                  // compute quad q
            v = (v >= 0.f) ? v : v * SLOPE;
            float ex = __expf(v);
            ex = (eb + sub < e1) ? ex : 0.f;
            s += ex;
            #pragma unroll
            for (int j = 0; j < 8; ++j) x[j] = fmaf(ex, (float)fr_0[j], x[j]);
            // rotate
            lv_0 = lv_1; fr_0 = fr_1;
            lv_1 = lv_2; fr_1 = fr_2;
            lv_2 = lv_3; fr_2 = fr_3;
            si_3 = si_4;
        }
    }

    // combine across edge-sub lanes (bits 4,5)
    s += __shfl_xor(s, 16); s += __shfl_xor(s, 32);
    #pragma unroll
    for (int j = 0; j < 8; ++j) {
        x[j] += __shfl_xor(x[j], 16);
        x[j] += __shfl_xor(x[j], 32);
    }
    const float inv = (s > 0.f) ? 1.f / s : 0.f;    // isolated node -> 0, matches ref
    if (sub == 0) {
        float4 v0 = make_float4(x[0] * inv, x[1] * inv, x[2] * inv, x[3] * inv);
        float4 v1 = make_float4(x[4] * inv, x[5] * inv, x[6] * inv, x[7] * inv);
        *reinterpret_cast<float4*>(&xb[p][t][c0]) = v0;
        *reinterpret_cast<float4*>(&xb[p][t][c0 + 4]) = v1;
    }
    __syncthreads();
    if (t == 0) {
        const int c = lane * 2;
        float a0 = xb[p][0][c] + xb[p][1][c] + b0[c] + b1[c];
        float a1 = xb[p][0][c + 1] + xb[p][1][c + 1] + b0[c + 1] + b1[c + 1];
        if (relu) { a0 = fmaxf(a0, 0.f); a1 = fmaxf(a1, 0.f); }
        union { f16 h2[2]; float f; } o;
        o.h2[0] = (f16)a0; o.h2[1] = (f16)a1;
        *reinterpret_cast<float*>(out + (size_t)n * 128 + c) = o.f;
    }
}

// ---------------- final linear (f16 input) ----------------
__global__ __launch_bounds__(256) void out_gemm_k(const f16* __restrict__ A,
                                                  const float* __restrict__ W,
                                                  const float* __restrict__ bout,
                                                  float* __restrict__ out) {
    __shared__ float At[16][132];
    const int row0 = blockIdx.x * 16;   // NN % 16 == 0
    const int t = threadIdx.x;
    {
        const int r = t >> 4, c8 = t & 15;
        const f16x8 v = *reinterpret_cast<const f16x8*>(A + (size_t)(row0 + r) * 128 + c8 * 8);
        #pragma unroll
        for (int j = 0; j < 8; ++j) At[r][c8 * 8 + j] = (float)v[j];
    }
    __syncthreads();
    const int r = t >> 4, c = t & 15;
    float accv = 0.f;
    #pragma unroll 8
    for (int k = 0; k < 128; ++k) accv = fmaf(At[r][k], W[k * 16 + c], accv);
    out[(row0 + r) * 16 + c] = accv + bout[c];
}

extern "C" void kernel_launch(void* const* d_in, const int* in_sizes, int n_in,
                              void* d_out, int out_size, void* d_ws, size_t ws_size,
                              hipStream_t stream) {
    (void)in_sizes; (void)n_in; (void)out_size; (void)ws_size;
    const float* x = (const float*)d_in[0];
    const int* src0 = (const int*)d_in[1];
    const int* dst0 = (const int*)d_in[2];
    const int* src1 = (const int*)d_in[3];
    const int* dst1 = (const int*)d_in[4];
    const float* W[3]  = {(const float*)d_in[5], (const float*)d_in[9],  (const float*)d_in[13]};
    const float* al[3] = {(const float*)d_in[6], (const float*)d_in[10], (const float*)d_in[14]};
    const float* ar[3] = {(const float*)d_in[7], (const float*)d_in[11], (const float*)d_in[15]};
    const float* bb[3] = {(const float*)d_in[8], (const float*)d_in[12], (const float*)d_in[16]};
    const float* Wout = (const float*)d_in[17];
    const float* bout = (const float*)d_in[18];
    float* outp = (float*)d_out;

    char* pb = (char*)d_ws;
    f16* feat   = (f16*)pb;    pb += (size_t)2 * NN * 128 * 2;   // [2][NN][128] fp16
    f16* hbuf   = (f16*)pb;    pb += (size_t)NN * 128 * 2;
    float* el   = (float*)pb;  pb += (size_t)2 * NN * HH * 4;
    float* er   = (float*)pb;  pb += (size_t)2 * NN * HH * 4;
    int* deg    = (int*)pb;    pb += (size_t)2 * NN * 4;
    int* cursor = (int*)pb;    pb += (size_t)2 * NN * 4;
    int* offs   = (int*)pb;    pb += (size_t)2 * (NN + 1) * 4;
    int* bsum   = (int*)pb;    pb += (size_t)2 * SCAN_NB * 4;
    f16* Wh     = (f16*)pb;    pb += (size_t)3 * 2 * 128 * 128 * 2;
    u16* csr    = (u16*)pb;    pb += (size_t)2 * EE * 2;

    // ---- setup: W convert + deg zero, then CSR build (scatter overlapped with gemm-1) ----
    prep_k<<<dim3(8, 2, 4), 256, 0, stream>>>(W[0], W[1], W[2], Wh, (int4*)deg);
    hist4_k<<<dim3((EE / 4 + 255) / 256, 2), 256, 0, stream>>>(dst0, dst1, deg);
    scan1_k<<<dim3(SCAN_NB, 2), 256, 0, stream>>>(deg, offs, bsum);
    scan3b_k<<<dim3(SCAN_NB, 2), 256, 0, stream>>>(offs, bsum, cursor);
    gemm1_scatter_k<<<2 * SCB + 938, 256, 0, stream>>>(x, Wh, al[0], ar[0], feat, el, er,
                                                       src0, dst0, src1, dst1, cursor, csr);

    // ---- layer-1 pull, then layers 2,3 ----
    pull_agg12_k<<<NN / 2, 256, 0, stream>>>(csr, offs, el, er, feat,
                                             bb[0], bb[0] + 128, hbuf, 1);
    for (int l = 1; l < 3; ++l) {
        gemm_mfma<<<938, 256, 0, stream>>>(
            hbuf, x, 0, Wh + l * 2 * 16384, al[l], ar[l], feat, el, er);
        pull_agg12_k<<<NN / 2, 256, 0, stream>>>(csr, offs, el, er, feat,
                                                 bb[l], bb[l] + 128, hbuf, (l < 2) ? 1 : 0);
    }
    out_gemm_k<<<NN / 16, 256, 0, stream>>>(hbuf, Wout, bout, outp);
}